// Round 1
// baseline (3351.470 us; speedup 1.0000x reference)
//
#include <hip/hip_runtime.h>
#include <hip/hip_bf16.h>
#include <stdint.h>

#define BB 2
#define TT 2048
#define DD 1024
#define NH 16
#define HD 64
#define TOPK 64
#define NEGF (-3.402823466e38f)

// ---------- helpers ----------
__device__ __forceinline__ uint32_t ord_u32(float x) {
    uint32_t b = __float_as_uint(x);
    return (b & 0x80000000u) ? ~b : (b | 0x80000000u);
}

__device__ __forceinline__ bool mask_at(const void* m, int mode, int idx) {
    if (mode == 0) return ((const int*)m)[idx] != 0;
    if (mode == 1) return ((const unsigned char*)m)[idx] != 0;
    return ((const float*)m)[idx] != 0.0f;
}

// ---------- mask dtype detection ----------
// int32 layout: bytes at (i%4)!=0 are all zero.
// bool layout : bytes are 0/1, some at (i%4)!=0 are 1 (mask ~10% ones).
// f32 layout  : bytes 0x80/0x3f appear -> values > 1.
__global__ void detect_kernel(const unsigned char* mask_raw, const int* causal_ptr, int* flags) {
    __shared__ int odd_nz, big;
    if (threadIdx.x == 0) { odd_nz = 0; big = 0; }
    __syncthreads();
    for (int i = threadIdx.x; i < BB * TT; i += blockDim.x) {
        unsigned char c = mask_raw[i];
        if ((i & 3) && c) atomicOr(&odd_nz, 1);
        if (c > 1) atomicOr(&big, 1);
    }
    __syncthreads();
    if (threadIdx.x == 0) {
        int mode = 0;
        if (odd_nz) mode = big ? 2 : 1;
        flags[0] = mode;
        flags[1] = (causal_ptr[0] != 0) ? 1 : 0;
    }
}

// ---------- f32 GEMM: C[m,n] = sum_k A[m,k]*W[n,k] + bias[n] ----------
// split_heads=1 -> write C as (B,H,T,HD); else row-major (M,N)
__global__ void __launch_bounds__(256) gemm_xwt(
    const float* __restrict__ A, const float* __restrict__ W,
    const float* __restrict__ bias, float* __restrict__ C,
    int M, int N, int K, int split_heads)
{
    __shared__ float As[64][17];
    __shared__ float Ws[64][17];
    const int tid = threadIdx.x;
    const int tx = tid & 15, ty = tid >> 4;
    const int arow = blockIdx.y * 64, bcol = blockIdx.x * 64;
    float acc[4][4] = {};

    for (int k0 = 0; k0 < K; k0 += 16) {
        const int r = tid >> 2, c = (tid & 3) * 4;
        float4 a4 = *(const float4*)(A + (size_t)(arow + r) * K + k0 + c);
        As[r][c] = a4.x; As[r][c + 1] = a4.y; As[r][c + 2] = a4.z; As[r][c + 3] = a4.w;
        float4 w4 = *(const float4*)(W + (size_t)(bcol + r) * K + k0 + c);
        Ws[r][c] = w4.x; Ws[r][c + 1] = w4.y; Ws[r][c + 2] = w4.z; Ws[r][c + 3] = w4.w;
        __syncthreads();
#pragma unroll
        for (int k = 0; k < 16; ++k) {
            float a0 = As[ty * 4 + 0][k], a1 = As[ty * 4 + 1][k];
            float a2 = As[ty * 4 + 2][k], a3 = As[ty * 4 + 3][k];
            float w0 = Ws[tx * 4 + 0][k], w1 = Ws[tx * 4 + 1][k];
            float w2 = Ws[tx * 4 + 2][k], w3 = Ws[tx * 4 + 3][k];
            acc[0][0] += a0 * w0; acc[0][1] += a0 * w1; acc[0][2] += a0 * w2; acc[0][3] += a0 * w3;
            acc[1][0] += a1 * w0; acc[1][1] += a1 * w1; acc[1][2] += a1 * w2; acc[1][3] += a1 * w3;
            acc[2][0] += a2 * w0; acc[2][1] += a2 * w1; acc[2][2] += a2 * w2; acc[2][3] += a2 * w3;
            acc[3][0] += a3 * w0; acc[3][1] += a3 * w1; acc[3][2] += a3 * w2; acc[3][3] += a3 * w3;
        }
        __syncthreads();
    }

#pragma unroll
    for (int i = 0; i < 4; ++i) {
        int m = arow + ty * 4 + i;
#pragma unroll
        for (int j = 0; j < 4; ++j) {
            int n = bcol + tx * 4 + j;
            float v = acc[i][j] + bias[n];
            if (split_heads) {
                int b = m / TT, t = m % TT, h = n / HD, dh = n % HD;
                C[(((size_t)b * NH + h) * TT + t) * HD + dh] = v;
            } else {
                C[(size_t)m * N + n] = v;
            }
        }
    }
}

// ---------- attention with exact top-64 ----------
__global__ void __launch_bounds__(256) attn_kernel(
    const float* __restrict__ Q, const float* __restrict__ K,
    const float* __restrict__ V, const void* __restrict__ maskp,
    const int* __restrict__ flags, float* __restrict__ O)
{
    __shared__ float slog[TT];
    __shared__ float qv[HD];
    __shared__ float red[256];
    __shared__ float wsel[128];
    __shared__ int   sel[128];
    __shared__ int   hist[256];
    __shared__ int   s_cnt;
    __shared__ uint32_t s_prefix;
    __shared__ int   s_kth;
    __shared__ float s_S;

    const int bid = blockIdx.x;
    const int qi = bid & (TT - 1);
    const int h  = (bid >> 11) & (NH - 1);
    const int b  = bid >> 15;
    const int tid = threadIdx.x;
    const int mode = flags[0], causal = flags[1];
    const size_t headbase = ((size_t)b * NH + h) * (size_t)TT * HD;

    if (tid < HD) qv[tid] = Q[headbase + (size_t)qi * HD + tid];
    __syncthreads();

    const float scale = 0.125f;  // 64^-0.5
    for (int j = tid; j < TT; j += 256) {
        bool blocked = (causal && j > qi) || mask_at(maskp, mode, b * TT + j);
        float lg;
        if (blocked) {
            lg = NEGF;
        } else {
            const float4* kr = (const float4*)(K + headbase + (size_t)j * HD);
            float acc = 0.f;
#pragma unroll
            for (int d = 0; d < 16; ++d) {
                float4 kk = kr[d];
                acc += qv[d * 4 + 0] * kk.x + qv[d * 4 + 1] * kk.y
                     + qv[d * 4 + 2] * kk.z + qv[d * 4 + 3] * kk.w;
            }
            lg = acc * scale;
        }
        slog[j] = lg;
    }
    __syncthreads();

    // row max
    float m = NEGF;
    for (int j = tid; j < TT; j += 256) m = fmaxf(m, slog[j]);
    red[tid] = m;
    __syncthreads();
    for (int s = 128; s > 0; s >>= 1) {
        if (tid < s) red[tid] = fmaxf(red[tid], red[tid + s]);
        __syncthreads();
    }
    m = red[0];
    __syncthreads();

    const int g = tid >> 6, d = tid & 63;

    if (m <= -3.0e38f) {
        // fully blocked row: reference softmax is uniform over ALL keys
        float acc = 0.f;
        for (int j = g; j < TT; j += 4) acc += V[headbase + (size_t)j * HD + d];
        red[tid] = acc;
        __syncthreads();
        if (g == 0) {
            float tot = red[d] + red[64 + d] + red[128 + d] + red[192 + d];
            O[((size_t)b * TT + qi) * DD + h * HD + d] = tot * (1.0f / TT);
        }
        return;
    }

    // exact 64th-largest via 4-pass radix select on order-preserving keys
    if (tid == 0) { s_prefix = 0; s_kth = TOPK; }
    __syncthreads();
    for (int pass = 3; pass >= 0; --pass) {
        const int shift = pass * 8;
        if (tid < 256) hist[tid] = 0;
        __syncthreads();
        uint32_t pref = s_prefix;
        for (int j = tid; j < TT; j += 256) {
            uint32_t u = ord_u32(slog[j]);
            bool match = (pass == 3) || ((u >> (shift + 8)) == (pref >> (shift + 8)));
            if (match) atomicAdd(&hist[(u >> shift) & 255], 1);
        }
        __syncthreads();
        if (tid == 0) {
            int kk = s_kth;
            int bsel = 0;
            for (int bi = 255; bi >= 0; --bi) {
                if (kk <= hist[bi]) { bsel = bi; break; }
                kk -= hist[bi];
            }
            s_kth = kk;
            s_prefix = pref | ((uint32_t)bsel << shift);
        }
        __syncthreads();
    }
    const uint32_t thr = s_prefix;

    // gather selected keys (w==0 entries -- e.g. masked NEG ties -- contribute
    // nothing to softmax; skip them so the compact list stays small)
    if (tid == 0) s_cnt = 0;
    __syncthreads();
    for (int j = tid; j < TT; j += 256) {
        uint32_t u = ord_u32(slog[j]);
        if (u >= thr) {
            float w = expf(slog[j] - m);
            if (w > 0.f) {
                int pos = atomicAdd(&s_cnt, 1);
                if (pos < 128) { sel[pos] = j; wsel[pos] = w; }
            }
        }
    }
    __syncthreads();
    int cnt = s_cnt; if (cnt > 128) cnt = 128;
    if (tid == 0) {
        float S = 0.f;
        for (int i = 0; i < cnt; ++i) S += wsel[i];
        s_S = S;
    }
    __syncthreads();

    // sparse A*V over selected keys
    float acc = 0.f;
    for (int i = g; i < cnt; i += 4) {
        acc += wsel[i] * V[headbase + (size_t)sel[i] * HD + d];
    }
    red[tid] = acc;
    __syncthreads();
    if (g == 0) {
        float tot = red[d] + red[64 + d] + red[128 + d] + red[192 + d];
        O[((size_t)b * TT + qi) * DD + h * HD + d] = tot / s_S;
    }
}

// ---------- launch ----------
extern "C" void kernel_launch(void* const* d_in, const int* in_sizes, int n_in,
                              void* d_out, int out_size, void* d_ws, size_t ws_size,
                              hipStream_t stream) {
    const float* x  = (const float*)d_in[0];
    const float* Wq = (const float*)d_in[1];
    const float* bq = (const float*)d_in[2];
    const float* Wk = (const float*)d_in[3];
    const float* bk = (const float*)d_in[4];
    const float* Wv = (const float*)d_in[5];
    const float* bv = (const float*)d_in[6];
    const float* Wo = (const float*)d_in[7];
    const float* bo = (const float*)d_in[8];
    const void*  maskp = d_in[9];
    const int*   causalp = (const int*)d_in[10];
    float* out = (float*)d_out;

    char* ws = (char*)d_ws;
    const size_t TEN = (size_t)BB * TT * DD * sizeof(float);  // 16 MB
    float* Q = (float*)(ws);
    float* K = (float*)(ws + TEN);
    float* V = (float*)(ws + 2 * TEN);
    float* O = (float*)(ws + 3 * TEN);
    int* flags = (int*)(ws + 4 * TEN);

    detect_kernel<<<1, 256, 0, stream>>>((const unsigned char*)maskp, causalp, flags);

    dim3 gg(DD / 64, (BB * TT) / 64);
    gemm_xwt<<<gg, 256, 0, stream>>>(x, Wq, bq, Q, BB * TT, DD, DD, 1);
    gemm_xwt<<<gg, 256, 0, stream>>>(x, Wk, bk, K, BB * TT, DD, DD, 1);
    gemm_xwt<<<gg, 256, 0, stream>>>(x, Wv, bv, V, BB * TT, DD, DD, 1);

    attn_kernel<<<BB * NH * TT, 256, 0, stream>>>(Q, K, V, maskp, flags, O);

    gemm_xwt<<<gg, 256, 0, stream>>>(O, Wo, bo, out, BB * TT, DD, DD, 0);
}

// Round 2
// 1876.060 us; speedup vs baseline: 1.7864x; 1.7864x over previous
//
#include <hip/hip_runtime.h>
#include <hip/hip_bf16.h>
#include <stdint.h>

#define BB 2
#define TT 2048
#define DD 1024
#define NH 16
#define HD 64
#define TOPK 64
#define NEGF (-3.402823466e38f)
#define ORD_NEG 0x00800000u  // ord_u32(NEGF)
#define QT 32                // q-rows per block
#define KT 256               // keys per LDS tile
#define KP 68                // padded floats per key row
#define SELCAP 96

// ---------- helpers ----------
__device__ __forceinline__ uint32_t ord_u32(float x) {
    uint32_t b = __float_as_uint(x);
    return (b & 0x80000000u) ? ~b : (b | 0x80000000u);
}
__device__ __forceinline__ float unord(uint32_t u) {
    uint32_t b = (u & 0x80000000u) ? (u ^ 0x80000000u) : ~u;
    return __uint_as_float(b);
}
__device__ __forceinline__ bool mask_at(const void* m, int mode, int idx) {
    if (mode == 0) return ((const int*)m)[idx] != 0;
    if (mode == 1) return ((const unsigned char*)m)[idx] != 0;
    return ((const float*)m)[idx] != 0.0f;
}

// ---------- mask dtype detection ----------
__global__ void detect_kernel(const unsigned char* mask_raw, const int* causal_ptr, int* flags) {
    __shared__ int odd_nz, big;
    if (threadIdx.x == 0) { odd_nz = 0; big = 0; }
    __syncthreads();
    for (int i = threadIdx.x; i < BB * TT; i += blockDim.x) {
        unsigned char c = mask_raw[i];
        if ((i & 3) && c) atomicOr(&odd_nz, 1);
        if (c > 1) atomicOr(&big, 1);
    }
    __syncthreads();
    if (threadIdx.x == 0) {
        int mode = 0;
        if (odd_nz) mode = big ? 2 : 1;
        flags[0] = mode;
        flags[1] = (causal_ptr[0] != 0) ? 1 : 0;
    }
}

// ---------- f32 GEMM: C[m,n] = sum_k A[m,k]*W[n,k] + bias[n] ----------
__global__ void __launch_bounds__(256) gemm_xwt(
    const float* __restrict__ A, const float* __restrict__ W,
    const float* __restrict__ bias, float* __restrict__ C,
    int M, int N, int K, int split_heads)
{
    __shared__ float As[64][17];
    __shared__ float Ws[64][17];
    const int tid = threadIdx.x;
    const int tx = tid & 15, ty = tid >> 4;
    const int arow = blockIdx.y * 64, bcol = blockIdx.x * 64;
    float acc[4][4] = {};

    for (int k0 = 0; k0 < K; k0 += 16) {
        const int r = tid >> 2, c = (tid & 3) * 4;
        float4 a4 = *(const float4*)(A + (size_t)(arow + r) * K + k0 + c);
        As[r][c] = a4.x; As[r][c + 1] = a4.y; As[r][c + 2] = a4.z; As[r][c + 3] = a4.w;
        float4 w4 = *(const float4*)(W + (size_t)(bcol + r) * K + k0 + c);
        Ws[r][c] = w4.x; Ws[r][c + 1] = w4.y; Ws[r][c + 2] = w4.z; Ws[r][c + 3] = w4.w;
        __syncthreads();
#pragma unroll
        for (int k = 0; k < 16; ++k) {
            float a0 = As[ty * 4 + 0][k], a1 = As[ty * 4 + 1][k];
            float a2 = As[ty * 4 + 2][k], a3 = As[ty * 4 + 3][k];
            float w0 = Ws[tx * 4 + 0][k], w1 = Ws[tx * 4 + 1][k];
            float w2 = Ws[tx * 4 + 2][k], w3 = Ws[tx * 4 + 3][k];
            acc[0][0] += a0 * w0; acc[0][1] += a0 * w1; acc[0][2] += a0 * w2; acc[0][3] += a0 * w3;
            acc[1][0] += a1 * w0; acc[1][1] += a1 * w1; acc[1][2] += a1 * w2; acc[1][3] += a1 * w3;
            acc[2][0] += a2 * w0; acc[2][1] += a2 * w1; acc[2][2] += a2 * w2; acc[2][3] += a2 * w3;
            acc[3][0] += a3 * w0; acc[3][1] += a3 * w1; acc[3][2] += a3 * w2; acc[3][3] += a3 * w3;
        }
        __syncthreads();
    }

#pragma unroll
    for (int i = 0; i < 4; ++i) {
        int m = arow + ty * 4 + i;
#pragma unroll
        for (int j = 0; j < 4; ++j) {
            int n = bcol + tx * 4 + j;
            float v = acc[i][j] + bias[n];
            if (split_heads) {
                int b = m / TT, t = m % TT, h = n / HD, dh = n % HD;
                C[(((size_t)b * NH + h) * TT + t) * HD + dh] = v;
            } else {
                C[(size_t)m * N + n] = v;
            }
        }
    }
}

// ---------- tiled attention with exact register-resident top-64 ----------
__global__ void __launch_bounds__(1024, 4) attn_topk(
    const float* __restrict__ Q, const float* __restrict__ K,
    const float* __restrict__ V, const void* __restrict__ maskp,
    const int* __restrict__ flags, float* __restrict__ O)
{
    __shared__ float k_lds[KT][KP];          // 69632 B
    __shared__ int   s_selk[QT][SELCAP];     // 12288 B
    __shared__ float s_selw[QT][SELCAP];     // 12288 B

    const int tid  = threadIdx.x;
    const int lane = tid & 63;
    const int wv   = tid >> 6;           // wave 0..15
    const int g    = lane >> 2;          // key offset within pass 0..15
    const int c    = lane & 3;           // 16-float chunk id
    const int qt   = blockIdx.x;         // 0..63
    const int bh   = blockIdx.y;         // 0..31
    const int b    = bh >> 4, h = bh & 15;
    const int mode = flags[0], causal = flags[1];
    const size_t hb = (size_t)bh * TT * HD;

    const int r0 = qt * QT + wv * 2;     // this wave's rows: r0, r0+1

    // q chunks in registers (16 floats per row per lane)
    float4 q4[2][4];
#pragma unroll
    for (int r = 0; r < 2; ++r)
#pragma unroll
        for (int i = 0; i < 4; ++i)
            q4[r][i] = *(const float4*)&Q[hb + (size_t)(r0 + r) * HD + c * 16 + i * 4];

    uint32_t lgo[2][32];                 // logits as order-preserving u32

    const int qmaxb = qt * QT + QT - 1;
    const int lastT = causal ? (qmaxb >> 8) : 7;
    const float scale = 0.125f;          // 64^-0.5

#pragma unroll
    for (int t = 0; t < 8; ++t) {
        if (t <= lastT) {
            __syncthreads();
            // stage KT keys -> LDS (coalesced global, padded LDS rows)
#pragma unroll
            for (int i = 0; i < 4; ++i) {
                int f  = tid + 1024 * i;   // float4 id 0..4095
                int kl = f >> 4, c4 = f & 15;
                *(float4*)&k_lds[kl][c4 * 4] =
                    *(const float4*)&K[hb + (size_t)(t * KT + kl) * HD + c4 * 4];
            }
            __syncthreads();
#pragma unroll
            for (int p = 0; p < 16; ++p) {
                int kl  = p * 16 + g;
                int key = t * KT + kl;
                const float4* kr = (const float4*)&k_lds[kl][c * 16];
                float4 k0 = kr[0], k1 = kr[1], k2 = kr[2], k3 = kr[3];
                float pr[2];
#pragma unroll
                for (int r = 0; r < 2; ++r) {
                    float4 a0 = q4[r][0], a1 = q4[r][1], a2 = q4[r][2], a3 = q4[r][3];
                    pr[r] = a0.x*k0.x + a0.y*k0.y + a0.z*k0.z + a0.w*k0.w
                          + a1.x*k1.x + a1.y*k1.y + a1.z*k1.z + a1.w*k1.w
                          + a2.x*k2.x + a2.y*k2.y + a2.z*k2.z + a2.w*k2.w
                          + a3.x*k3.x + a3.y*k3.y + a3.z*k3.z + a3.w*k3.w;
                }
                bool kpad = mask_at(maskp, mode, b * TT + key);
#pragma unroll
                for (int r = 0; r < 2; ++r) {
                    float s = pr[r];
                    s += __shfl_xor(s, 1, 64);
                    s += __shfl_xor(s, 2, 64);
                    float lg = (kpad || (causal && key > r0 + r)) ? NEGF : s * scale;
                    if ((p & 3) == c) lgo[r][t * 4 + (p >> 2)] = ord_u32(lg);
                }
            }
        } else {
#pragma unroll
            for (int s2 = 0; s2 < 4; ++s2) {
                lgo[0][t * 4 + s2] = ORD_NEG;
                lgo[1][t * 4 + s2] = ORD_NEG;
            }
        }
    }

    // ---- per-row epilogue: exact top-64 select + softmax + sparse A*V ----
#pragma unroll
    for (int r = 0; r < 2; ++r) {
        const int row = r0 + r;
        // row max (ord) + valid count
        uint32_t mo = 0; int nv = 0;
#pragma unroll
        for (int i = 0; i < 32; ++i) {
            uint32_t u = lgo[r][i];
            mo = mo > u ? mo : u;
            nv += (u > ORD_NEG) ? 1 : 0;
        }
#pragma unroll
        for (int off = 1; off < 64; off <<= 1) {
            uint32_t mu = (uint32_t)__shfl_xor((int)mo, off, 64);
            mo = mo > mu ? mo : mu;
            nv += __shfl_xor(nv, off, 64);
        }

        float outv;
        if (nv == 0) {
            // fully blocked row: reference softmax is uniform over ALL keys
            float acc = 0.f;
            for (int j = 0; j < TT; j += 8) {
#pragma unroll
                for (int jj = 0; jj < 8; ++jj)
                    acc += V[hb + (size_t)(j + jj) * HD + lane];
            }
            outv = acc * (1.0f / TT);
        } else {
            const float m = unord(mo);
            uint32_t thr = 0u;
            if (nv > TOPK) {
                // exact 64th-largest: binary search on ord keys, wave-parallel count
                uint32_t lo = 0u, hi = 0xFFFFFFFFu;
                while (hi - lo > 1u) {
                    uint32_t mid = lo + ((hi - lo) >> 1);
                    int cgt = 0;
#pragma unroll
                    for (int i = 0; i < 32; ++i) cgt += (lgo[r][i] >= mid) ? 1 : 0;
#pragma unroll
                    for (int off = 1; off < 64; off <<= 1) cgt += __shfl_xor(cgt, off, 64);
                    if (cgt >= TOPK) lo = mid; else hi = mid;
                }
                thr = lo;
            }
            // weights pass 1: overwrite lgo with w bits
            int nsel = 0; float Sp = 0.f;
#pragma unroll
            for (int i = 0; i < 32; ++i) {
                uint32_t u = lgo[r][i];
                float w = 0.f;
                if (u >= thr) w = expf(unord(u) - m);  // blocked: expf(-3.4e38)=0
                Sp += w;
                nsel += (w > 0.f) ? 1 : 0;
                lgo[r][i] = (w > 0.f) ? __float_as_uint(w) : 0u;
            }
            float S = Sp;
#pragma unroll
            for (int off = 1; off < 64; off <<= 1) S += __shfl_xor(S, off, 64);
            // exclusive scan of nsel over lanes -> append offsets (no atomics)
            int incl = nsel;
#pragma unroll
            for (int off = 1; off < 64; off <<= 1) {
                int t2 = __shfl_up(incl, off, 64);
                if (lane >= off) incl += t2;
            }
            int base = incl - nsel;
            int cnt  = __shfl(incl, 63, 64);
            // pass 2: append selected (key, w)
            int pos = base;
#pragma unroll
            for (int i = 0; i < 32; ++i) {
                float w = __uint_as_float(lgo[r][i]);
                if (w > 0.f) {
                    if (pos < SELCAP) {
                        int key = (i >> 2) * KT + (((i & 3) * 4 + c) * 16) + g;
                        s_selk[wv * 2 + r][pos] = key;
                        s_selw[wv * 2 + r][pos] = w;
                    }
                    ++pos;
                }
            }
            if (cnt > SELCAP) cnt = SELCAP;
            // sparse A*V: lane = output dim, coalesced 256B V reads
            float acc = 0.f;
            int i2 = 0;
            for (; i2 + 4 <= cnt; i2 += 4) {
                int   ka = s_selk[wv * 2 + r][i2],     kb = s_selk[wv * 2 + r][i2 + 1];
                int   kc2 = s_selk[wv * 2 + r][i2 + 2], kd = s_selk[wv * 2 + r][i2 + 3];
                float wa = s_selw[wv * 2 + r][i2],     wb = s_selw[wv * 2 + r][i2 + 1];
                float wc = s_selw[wv * 2 + r][i2 + 2], wd = s_selw[wv * 2 + r][i2 + 3];
                acc += wa * V[hb + (size_t)ka * HD + lane];
                acc += wb * V[hb + (size_t)kb * HD + lane];
                acc += wc * V[hb + (size_t)kc2 * HD + lane];
                acc += wd * V[hb + (size_t)kd * HD + lane];
            }
            for (; i2 < cnt; ++i2) {
                acc += s_selw[wv * 2 + r][i2] * V[hb + (size_t)s_selk[wv * 2 + r][i2] * HD + lane];
            }
            outv = acc / S;
        }
        O[((size_t)b * TT + row) * DD + h * HD + lane] = outv;
    }
}

// ---------- launch ----------
extern "C" void kernel_launch(void* const* d_in, const int* in_sizes, int n_in,
                              void* d_out, int out_size, void* d_ws, size_t ws_size,
                              hipStream_t stream) {
    const float* x  = (const float*)d_in[0];
    const float* Wq = (const float*)d_in[1];
    const float* bq = (const float*)d_in[2];
    const float* Wk = (const float*)d_in[3];
    const float* bk = (const float*)d_in[4];
    const float* Wv = (const float*)d_in[5];
    const float* bv = (const float*)d_in[6];
    const float* Wo = (const float*)d_in[7];
    const float* bo = (const float*)d_in[8];
    const void*  maskp = d_in[9];
    const int*   causalp = (const int*)d_in[10];
    float* out = (float*)d_out;

    char* ws = (char*)d_ws;
    const size_t TEN = (size_t)BB * TT * DD * sizeof(float);  // 16 MB
    float* Q = (float*)(ws);
    float* K = (float*)(ws + TEN);
    float* V = (float*)(ws + 2 * TEN);
    float* O = (float*)(ws + 3 * TEN);
    int* flags = (int*)(ws + 4 * TEN);

    detect_kernel<<<1, 256, 0, stream>>>((const unsigned char*)maskp, causalp, flags);

    dim3 gg(DD / 64, (BB * TT) / 64);
    gemm_xwt<<<gg, 256, 0, stream>>>(x, Wq, bq, Q, BB * TT, DD, DD, 1);
    gemm_xwt<<<gg, 256, 0, stream>>>(x, Wk, bk, K, BB * TT, DD, DD, 1);
    gemm_xwt<<<gg, 256, 0, stream>>>(x, Wv, bv, V, BB * TT, DD, DD, 1);

    dim3 ag(TT / QT, BB * NH);
    attn_topk<<<ag, 1024, 0, stream>>>(Q, K, V, maskp, flags, O);

    gemm_xwt<<<gg, 256, 0, stream>>>(O, Wo, bo, out, BB * TT, DD, DD, 0);
}

// Round 3
// 1409.860 us; speedup vs baseline: 2.3772x; 1.3307x over previous
//
#include <hip/hip_runtime.h>
#include <hip/hip_bf16.h>
#include <stdint.h>

#define BB 2
#define TT 2048
#define DD 1024
#define NH 16
#define HD 64
#define TOPK 64
#define NEGF (-3.402823466e38f)
#define ORD_NEG 0x00800000u  // ord_u32(NEGF)
#define QT 16                // q-rows per block (1 per wave)
#define KT 256               // keys per tile
#define SELCAP 96

typedef short short8x __attribute__((ext_vector_type(8)));
typedef float floatx4 __attribute__((ext_vector_type(4)));

// ---------- helpers ----------
__device__ __forceinline__ uint32_t ord_u32(float x) {
    uint32_t b = __float_as_uint(x);
    return (b & 0x80000000u) ? ~b : (b | 0x80000000u);
}
__device__ __forceinline__ float unord(uint32_t u) {
    uint32_t b = (u & 0x80000000u) ? (u ^ 0x80000000u) : ~u;
    return __uint_as_float(b);
}
__device__ __forceinline__ short bf16_rne(float x) {
    uint32_t u = __float_as_uint(x);
    u += 0x7FFFu + ((u >> 16) & 1u);
    return (short)(u >> 16);
}
__device__ __forceinline__ float bf16_to_f(short h) {
    return __uint_as_float(((uint32_t)(uint16_t)h) << 16);
}
__device__ __forceinline__ bool mask_at(const void* m, int mode, int idx) {
    if (mode == 0) return ((const int*)m)[idx] != 0;
    if (mode == 1) return ((const unsigned char*)m)[idx] != 0;
    return ((const float*)m)[idx] != 0.0f;
}

// ---------- mask dtype detection ----------
__global__ void detect_kernel(const unsigned char* mask_raw, const int* causal_ptr, int* flags) {
    __shared__ int odd_nz, big;
    if (threadIdx.x == 0) { odd_nz = 0; big = 0; }
    __syncthreads();
    for (int i = threadIdx.x; i < BB * TT; i += blockDim.x) {
        unsigned char c = mask_raw[i];
        if ((i & 3) && c) atomicOr(&odd_nz, 1);
        if (c > 1) atomicOr(&big, 1);
    }
    __syncthreads();
    if (threadIdx.x == 0) {
        int mode = 0;
        if (odd_nz) mode = big ? 2 : 1;
        flags[0] = mode;
        flags[1] = (causal_ptr[0] != 0) ? 1 : 0;
    }
}

// ---------- f32 GEMM: C[m,n] = sum_k A[m,k]*W[n,k] + bias[n] ----------
__global__ void __launch_bounds__(256) gemm_xwt(
    const float* __restrict__ A, const float* __restrict__ W,
    const float* __restrict__ bias, float* __restrict__ C,
    int M, int N, int K, int split_heads)
{
    __shared__ float As[64][17];
    __shared__ float Ws[64][17];
    const int tid = threadIdx.x;
    const int tx = tid & 15, ty = tid >> 4;
    const int arow = blockIdx.y * 64, bcol = blockIdx.x * 64;
    float acc[4][4] = {};

    for (int k0 = 0; k0 < K; k0 += 16) {
        const int r = tid >> 2, c = (tid & 3) * 4;
        float4 a4 = *(const float4*)(A + (size_t)(arow + r) * K + k0 + c);
        As[r][c] = a4.x; As[r][c + 1] = a4.y; As[r][c + 2] = a4.z; As[r][c + 3] = a4.w;
        float4 w4 = *(const float4*)(W + (size_t)(bcol + r) * K + k0 + c);
        Ws[r][c] = w4.x; Ws[r][c + 1] = w4.y; Ws[r][c + 2] = w4.z; Ws[r][c + 3] = w4.w;
        __syncthreads();
#pragma unroll
        for (int k = 0; k < 16; ++k) {
            float a0 = As[ty * 4 + 0][k], a1 = As[ty * 4 + 1][k];
            float a2 = As[ty * 4 + 2][k], a3 = As[ty * 4 + 3][k];
            float w0 = Ws[tx * 4 + 0][k], w1 = Ws[tx * 4 + 1][k];
            float w2 = Ws[tx * 4 + 2][k], w3 = Ws[tx * 4 + 3][k];
            acc[0][0] += a0 * w0; acc[0][1] += a0 * w1; acc[0][2] += a0 * w2; acc[0][3] += a0 * w3;
            acc[1][0] += a1 * w0; acc[1][1] += a1 * w1; acc[1][2] += a1 * w2; acc[1][3] += a1 * w3;
            acc[2][0] += a2 * w0; acc[2][1] += a2 * w1; acc[2][2] += a2 * w2; acc[2][3] += a2 * w3;
            acc[3][0] += a3 * w0; acc[3][1] += a3 * w1; acc[3][2] += a3 * w2; acc[3][3] += a3 * w3;
        }
        __syncthreads();
    }

#pragma unroll
    for (int i = 0; i < 4; ++i) {
        int m = arow + ty * 4 + i;
#pragma unroll
        for (int j = 0; j < 4; ++j) {
            int n = bcol + tx * 4 + j;
            float v = acc[i][j] + bias[n];
            if (split_heads) {
                int b = m / TT, t = m % TT, h = n / HD, dh = n % HD;
                C[(((size_t)b * NH + h) * TT + t) * HD + dh] = v;
            } else {
                C[(size_t)m * N + n] = v;
            }
        }
    }
}

// ---------- MFMA attention with exact register-resident top-64 ----------
__global__ void __launch_bounds__(1024) attn_topk(
    const float* __restrict__ Q, const float* __restrict__ K,
    const float* __restrict__ V, const void* __restrict__ maskp,
    const int* __restrict__ flags, float* __restrict__ O)
{
    __shared__ float s_S[QT][KT + 1];        // 16 x 257 f32 = 16.4 KB
    __shared__ int   s_selk[QT][SELCAP];
    __shared__ float s_selw[QT][SELCAP];

    const int tid = threadIdx.x, lane = tid & 63, wv = tid >> 6;
    const int qt = blockIdx.x, bh = blockIdx.y;
    const int b = bh >> 4, h = bh & 15;
    const int mode = flags[0], causal = flags[1];
    const size_t hb = (size_t)bh * (size_t)TT * HD;
    const int r0 = qt * QT;
    const int gq = r0 + wv;              // this wave's q row (global)

    // ---- Q fragments (scaled by dh^-0.5, split hi/lo bf16) ----
    // A-frag (16x16x32): lane l -> row = l&15, k = (l>>4)*8 + j (+ kh*32)
    short8x qhi[2], qlo[2];
#pragma unroll
    for (int kh = 0; kh < 2; ++kh) {
        const float* qp = Q + hb + (size_t)(r0 + (lane & 15)) * HD + (lane >> 4) * 8 + kh * 32;
        float4 a = *(const float4*)qp, c = *(const float4*)(qp + 4);
        float f[8] = {a.x, a.y, a.z, a.w, c.x, c.y, c.z, c.w};
#pragma unroll
        for (int i = 0; i < 8; ++i) {
            float x = f[i] * 0.125f;
            short hi16 = bf16_rne(x);
            qhi[kh][i] = hi16;
            qlo[kh][i] = bf16_rne(x - bf16_to_f(hi16));
        }
    }

    // ---- mask bits: lane's 32 keys, key = (i>>2)*KT + (i&3)*64 + lane ----
    uint32_t mbits = 0;
#pragma unroll
    for (int i = 0; i < 32; ++i) {
        int key = (i >> 2) * KT + (i & 3) * 64 + lane;
        if (mask_at(maskp, mode, b * TT + key)) mbits |= (1u << i);
    }

    uint32_t lgo[32];
#pragma unroll
    for (int i = 0; i < 32; ++i) lgo[i] = ORD_NEG;

    const int lastT = causal ? ((r0 + QT - 1) >> 8) : 7;

#pragma unroll
    for (int t = 0; t < 8; ++t) {
        if (t <= lastT) {                 // block-uniform
            __syncthreads();              // prev tile's S reads done
            // B-frag: lane l -> col(key) = t*KT + wv*16 + (l&15), k = (l>>4)*8 + j
            const float* kp = K + hb + (size_t)(t * KT + wv * 16 + (lane & 15)) * HD + (lane >> 4) * 8;
            float4 k0 = *(const float4*)kp,        k1 = *(const float4*)(kp + 4);
            float4 k2 = *(const float4*)(kp + 32), k3 = *(const float4*)(kp + 36);
            float f0[8] = {k0.x, k0.y, k0.z, k0.w, k1.x, k1.y, k1.z, k1.w};
            float f1[8] = {k2.x, k2.y, k2.z, k2.w, k3.x, k3.y, k3.z, k3.w};
            short8x bhi0, blo0, bhi1, blo1;
#pragma unroll
            for (int i = 0; i < 8; ++i) {
                short h0 = bf16_rne(f0[i]); bhi0[i] = h0; blo0[i] = bf16_rne(f0[i] - bf16_to_f(h0));
                short h1 = bf16_rne(f1[i]); bhi1[i] = h1; blo1[i] = bf16_rne(f1[i] - bf16_to_f(h1));
            }
            floatx4 acc = {0.f, 0.f, 0.f, 0.f};
            acc = __builtin_amdgcn_mfma_f32_16x16x32_bf16(qhi[0], bhi0, acc, 0, 0, 0);
            acc = __builtin_amdgcn_mfma_f32_16x16x32_bf16(qhi[0], blo0, acc, 0, 0, 0);
            acc = __builtin_amdgcn_mfma_f32_16x16x32_bf16(qlo[0], bhi0, acc, 0, 0, 0);
            acc = __builtin_amdgcn_mfma_f32_16x16x32_bf16(qhi[1], bhi1, acc, 0, 0, 0);
            acc = __builtin_amdgcn_mfma_f32_16x16x32_bf16(qhi[1], blo1, acc, 0, 0, 0);
            acc = __builtin_amdgcn_mfma_f32_16x16x32_bf16(qlo[1], bhi1, acc, 0, 0, 0);
            // C: col = lane&15, row = (lane>>4)*4 + j
#pragma unroll
            for (int j = 0; j < 4; ++j)
                s_S[(lane >> 4) * 4 + j][wv * 16 + (lane & 15)] = acc[j];
            __syncthreads();
            // read back own row, apply masks, store ord keys
#pragma unroll
            for (int j = 0; j < 4; ++j) {
                float sv = s_S[wv][j * 64 + lane];
                int key = t * KT + j * 64 + lane;
                bool blocked = ((mbits >> (t * 4 + j)) & 1u) || (causal && key > gq);
                lgo[t * 4 + j] = blocked ? ORD_NEG : ord_u32(sv);
            }
        }
    }

    // ---- epilogue: exact top-64 select + softmax + sparse A*V ----
    uint32_t mo = 0; int nv = 0;
#pragma unroll
    for (int i = 0; i < 32; ++i) {
        uint32_t u = lgo[i];
        mo = u > mo ? u : mo;
        nv += (u > ORD_NEG) ? 1 : 0;
    }
#pragma unroll
    for (int off = 1; off < 64; off <<= 1) {
        uint32_t mu = (uint32_t)__shfl_xor((int)mo, off, 64);
        mo = mu > mo ? mu : mo;
        nv += __shfl_xor(nv, off, 64);
    }

    float outv;
    if (nv == 0) {
        // fully blocked row: reference softmax is uniform over ALL keys
        float a0 = 0.f, a1 = 0.f, a2 = 0.f, a3 = 0.f;
        for (int j = 0; j < TT; j += 4) {
            a0 += V[hb + (size_t)(j + 0) * HD + lane];
            a1 += V[hb + (size_t)(j + 1) * HD + lane];
            a2 += V[hb + (size_t)(j + 2) * HD + lane];
            a3 += V[hb + (size_t)(j + 3) * HD + lane];
        }
        outv = (a0 + a1 + a2 + a3) * (1.0f / TT);
    } else {
        const float m = unord(mo);
        // clip search to [m-15, m]: dropped keys have w < e^-15 (error < 1e-4)
        uint32_t lo = ord_u32(m - 15.0f);
        int c0 = 0;
#pragma unroll
        for (int i = 0; i < 32; ++i) c0 += (lgo[i] >= lo) ? 1 : 0;
#pragma unroll
        for (int off = 1; off < 64; off <<= 1) c0 += __shfl_xor(c0, off, 64);

        uint32_t thr = lo;
        if (c0 > TOPK) {
            uint32_t hi = mo;   // count(mo) = max multiplicity (~1) < 64
            while (hi - lo > 1u) {
                uint32_t mid = lo + ((hi - lo) >> 1);
                int c = 0;
#pragma unroll
                for (int i = 0; i < 32; ++i) c += (lgo[i] >= mid) ? 1 : 0;
#pragma unroll
                for (int off = 1; off < 64; off <<= 1) c += __shfl_xor(c, off, 64);
                if (c == TOPK) { lo = mid; break; }
                if (c > TOPK) lo = mid; else hi = mid;
            }
            thr = lo;
        }

        // weights: overwrite lgo with w bits
        int nsel = 0; float Sp = 0.f;
#pragma unroll
        for (int i = 0; i < 32; ++i) {
            uint32_t u = lgo[i];
            float w = 0.f;
            if (u >= thr) w = __expf(unord(u) - m);
            Sp += w;
            nsel += (w > 0.f) ? 1 : 0;
            lgo[i] = (w > 0.f) ? __float_as_uint(w) : 0u;
        }
        float S = Sp;
#pragma unroll
        for (int off = 1; off < 64; off <<= 1) S += __shfl_xor(S, off, 64);
        // exclusive scan of nsel -> append offsets
        int incl = nsel;
#pragma unroll
        for (int off = 1; off < 64; off <<= 1) {
            int t2 = __shfl_up(incl, off, 64);
            if (lane >= off) incl += t2;
        }
        int base = incl - nsel;
        int cnt  = __shfl(incl, 63, 64);
        int pos = base;
#pragma unroll
        for (int i = 0; i < 32; ++i) {
            float w = __uint_as_float(lgo[i]);
            if (w > 0.f) {
                if (pos < SELCAP) {
                    s_selk[wv][pos] = (i >> 2) * KT + (i & 3) * 64 + lane;
                    s_selw[wv][pos] = w;
                }
                ++pos;
            }
        }
        if (cnt > SELCAP) cnt = SELCAP;
        // sparse A*V: lane = output dim, coalesced 256B V reads (wave-private row)
        float acc = 0.f;
        int i2 = 0;
        for (; i2 + 4 <= cnt; i2 += 4) {
            int   ka = s_selk[wv][i2],     kb = s_selk[wv][i2 + 1];
            int   kc = s_selk[wv][i2 + 2], kd = s_selk[wv][i2 + 3];
            float wa = s_selw[wv][i2],     wb = s_selw[wv][i2 + 1];
            float wc = s_selw[wv][i2 + 2], wd = s_selw[wv][i2 + 3];
            acc += wa * V[hb + (size_t)ka * HD + lane];
            acc += wb * V[hb + (size_t)kb * HD + lane];
            acc += wc * V[hb + (size_t)kc * HD + lane];
            acc += wd * V[hb + (size_t)kd * HD + lane];
        }
        for (; i2 < cnt; ++i2)
            acc += s_selw[wv][i2] * V[hb + (size_t)s_selk[wv][i2] * HD + lane];
        outv = acc / S;
    }
    O[((size_t)b * TT + gq) * DD + h * HD + lane] = outv;
}

// ---------- launch ----------
extern "C" void kernel_launch(void* const* d_in, const int* in_sizes, int n_in,
                              void* d_out, int out_size, void* d_ws, size_t ws_size,
                              hipStream_t stream) {
    const float* x  = (const float*)d_in[0];
    const float* Wq = (const float*)d_in[1];
    const float* bq = (const float*)d_in[2];
    const float* Wk = (const float*)d_in[3];
    const float* bk = (const float*)d_in[4];
    const float* Wv = (const float*)d_in[5];
    const float* bv = (const float*)d_in[6];
    const float* Wo = (const float*)d_in[7];
    const float* bo = (const float*)d_in[8];
    const void*  maskp = d_in[9];
    const int*   causalp = (const int*)d_in[10];
    float* out = (float*)d_out;

    char* ws = (char*)d_ws;
    const size_t TEN = (size_t)BB * TT * DD * sizeof(float);  // 16 MB
    float* Q = (float*)(ws);
    float* K = (float*)(ws + TEN);
    float* V = (float*)(ws + 2 * TEN);
    float* O = (float*)(ws + 3 * TEN);
    int* flags = (int*)(ws + 4 * TEN);

    detect_kernel<<<1, 256, 0, stream>>>((const unsigned char*)maskp, causalp, flags);

    dim3 gg(DD / 64, (BB * TT) / 64);
    gemm_xwt<<<gg, 256, 0, stream>>>(x, Wq, bq, Q, BB * TT, DD, DD, 1);
    gemm_xwt<<<gg, 256, 0, stream>>>(x, Wk, bk, K, BB * TT, DD, DD, 1);
    gemm_xwt<<<gg, 256, 0, stream>>>(x, Wv, bv, V, BB * TT, DD, DD, 1);

    dim3 ag(TT / QT, BB * NH);
    attn_topk<<<ag, 1024, 0, stream>>>(Q, K, V, maskp, flags, O);

    gemm_xwt<<<gg, 256, 0, stream>>>(O, Wo, bo, out, BB * TT, DD, DD, 0);
}

// Round 4
// 1058.021 us; speedup vs baseline: 3.1677x; 1.3325x over previous
//
#include <hip/hip_runtime.h>
#include <hip/hip_bf16.h>
#include <stdint.h>

#define BB 2
#define TT 2048
#define DD 1024
#define NH 16
#define HD 64
#define TOPK 64
#define NEGF (-3.402823466e38f)
#define ORD_NEG 0x00800000u  // ord_u32(NEGF)
#define QT 16                // q-rows per block (1 per wave)
#define KT 256               // keys per tile
#define SELCAP 96

typedef short short8x __attribute__((ext_vector_type(8)));
typedef float floatx4 __attribute__((ext_vector_type(4)));

// ---------- helpers ----------
__device__ __forceinline__ uint32_t ord_u32(float x) {
    uint32_t b = __float_as_uint(x);
    return (b & 0x80000000u) ? ~b : (b | 0x80000000u);
}
__device__ __forceinline__ float unord(uint32_t u) {
    uint32_t b = (u & 0x80000000u) ? (u ^ 0x80000000u) : ~u;
    return __uint_as_float(b);
}
__device__ __forceinline__ short bf16_rne(float x) {
    uint32_t u = __float_as_uint(x);
    u += 0x7FFFu + ((u >> 16) & 1u);
    return (short)(u >> 16);
}
__device__ __forceinline__ float bf16_to_f(short h) {
    return __uint_as_float(((uint32_t)(uint16_t)h) << 16);
}
__device__ __forceinline__ bool mask_at(const void* m, int mode, int idx) {
    if (mode == 0) return ((const int*)m)[idx] != 0;
    if (mode == 1) return ((const unsigned char*)m)[idx] != 0;
    return ((const float*)m)[idx] != 0.0f;
}

// ---------- mask dtype detection ----------
__global__ void detect_kernel(const unsigned char* mask_raw, const int* causal_ptr, int* flags) {
    __shared__ int odd_nz, big;
    if (threadIdx.x == 0) { odd_nz = 0; big = 0; }
    __syncthreads();
    for (int i = threadIdx.x; i < BB * TT; i += blockDim.x) {
        unsigned char c = mask_raw[i];
        if ((i & 3) && c) atomicOr(&odd_nz, 1);
        if (c > 1) atomicOr(&big, 1);
    }
    __syncthreads();
    if (threadIdx.x == 0) {
        int mode = 0;
        if (odd_nz) mode = big ? 2 : 1;
        flags[0] = mode;
        flags[1] = (causal_ptr[0] != 0) ? 1 : 0;
    }
}

// ---------- f32 -> (hi, lo) bf16 split ----------
__global__ void __launch_bounds__(256) split_f32(
    const float* __restrict__ in, short* __restrict__ hi, short* __restrict__ lo, int n4)
{
    int i = blockIdx.x * blockDim.x + threadIdx.x;
    if (i >= n4) return;
    float4 v = ((const float4*)in)[i];
    float f[4] = {v.x, v.y, v.z, v.w};
    short hh[4], ll[4];
#pragma unroll
    for (int j = 0; j < 4; ++j) {
        hh[j] = bf16_rne(f[j]);
        ll[j] = bf16_rne(f[j] - bf16_to_f(hh[j]));
    }
    short4 h4; h4.x = hh[0]; h4.y = hh[1]; h4.z = hh[2]; h4.w = hh[3];
    short4 l4; l4.x = ll[0]; l4.y = ll[1]; l4.z = ll[2]; l4.w = ll[3];
    ((short4*)hi)[i] = h4;
    ((short4*)lo)[i] = l4;
}

// ---------- split-bf16 MFMA GEMM: C[m,n] = sum_k A[m,k]*W[n,k] + bias[n] ----------
// Fixed shape M=BB*TT=4096, N=DD, K=DD. LDS-free: fragments straight from L2.
__global__ void __launch_bounds__(256) gemm_bf16s(
    const short* __restrict__ Ah, const short* __restrict__ Al,
    const short* __restrict__ Bh, const short* __restrict__ Bl,
    const float* __restrict__ bias, float* __restrict__ C, int split_heads)
{
    const int tid = threadIdx.x, lane = tid & 63, wv = tid >> 6;
    const int wr = wv >> 1, wc = wv & 1;
    const int m0 = blockIdx.y * 128 + wr * 64;
    const int n0 = blockIdx.x * 64 + wc * 32;
    const int lrow = lane & 15, lk = (lane >> 4) * 8;

    floatx4 acc[4][2];
#pragma unroll
    for (int i = 0; i < 4; ++i)
#pragma unroll
        for (int j = 0; j < 2; ++j) acc[i][j] = (floatx4){0.f, 0.f, 0.f, 0.f};

    for (int kk = 0; kk < DD; kk += 32) {
        short8x ah[4], al[4], bh[2], bl[2];
#pragma unroll
        for (int mb = 0; mb < 4; ++mb) {
            size_t off = (size_t)(m0 + mb * 16 + lrow) * DD + kk + lk;
            ah[mb] = *(const short8x*)(Ah + off);
            al[mb] = *(const short8x*)(Al + off);
        }
#pragma unroll
        for (int nb = 0; nb < 2; ++nb) {
            size_t off = (size_t)(n0 + nb * 16 + lrow) * DD + kk + lk;
            bh[nb] = *(const short8x*)(Bh + off);
            bl[nb] = *(const short8x*)(Bl + off);
        }
#pragma unroll
        for (int mb = 0; mb < 4; ++mb)
#pragma unroll
            for (int nb = 0; nb < 2; ++nb) {
                acc[mb][nb] = __builtin_amdgcn_mfma_f32_16x16x32_bf16(ah[mb], bh[nb], acc[mb][nb], 0, 0, 0);
                acc[mb][nb] = __builtin_amdgcn_mfma_f32_16x16x32_bf16(ah[mb], bl[nb], acc[mb][nb], 0, 0, 0);
                acc[mb][nb] = __builtin_amdgcn_mfma_f32_16x16x32_bf16(al[mb], bh[nb], acc[mb][nb], 0, 0, 0);
            }
    }

#pragma unroll
    for (int mb = 0; mb < 4; ++mb)
#pragma unroll
        for (int nb = 0; nb < 2; ++nb) {
            int n = n0 + nb * 16 + lrow;
            float bv = bias[n];
#pragma unroll
            for (int j = 0; j < 4; ++j) {
                int m = m0 + mb * 16 + (lane >> 4) * 4 + j;
                float v = acc[mb][nb][j] + bv;
                if (split_heads) {
                    int b = m >> 11, t = m & (TT - 1), h = n >> 6, dh = n & (HD - 1);
                    C[(((size_t)b * NH + h) * TT + t) * HD + dh] = v;
                } else {
                    C[(size_t)m * DD + n] = v;
                }
            }
        }
}

// ---------- f32 GEMM (fallback if workspace too small) ----------
__global__ void __launch_bounds__(256) gemm_xwt(
    const float* __restrict__ A, const float* __restrict__ W,
    const float* __restrict__ bias, float* __restrict__ C,
    int M, int N, int K, int split_heads)
{
    __shared__ float As[64][17];
    __shared__ float Ws[64][17];
    const int tid = threadIdx.x;
    const int tx = tid & 15, ty = tid >> 4;
    const int arow = blockIdx.y * 64, bcol = blockIdx.x * 64;
    float acc[4][4] = {};

    for (int k0 = 0; k0 < K; k0 += 16) {
        const int r = tid >> 2, c = (tid & 3) * 4;
        float4 a4 = *(const float4*)(A + (size_t)(arow + r) * K + k0 + c);
        As[r][c] = a4.x; As[r][c + 1] = a4.y; As[r][c + 2] = a4.z; As[r][c + 3] = a4.w;
        float4 w4 = *(const float4*)(W + (size_t)(bcol + r) * K + k0 + c);
        Ws[r][c] = w4.x; Ws[r][c + 1] = w4.y; Ws[r][c + 2] = w4.z; Ws[r][c + 3] = w4.w;
        __syncthreads();
#pragma unroll
        for (int k = 0; k < 16; ++k) {
            float a0 = As[ty * 4 + 0][k], a1 = As[ty * 4 + 1][k];
            float a2 = As[ty * 4 + 2][k], a3 = As[ty * 4 + 3][k];
            float w0 = Ws[tx * 4 + 0][k], w1 = Ws[tx * 4 + 1][k];
            float w2 = Ws[tx * 4 + 2][k], w3 = Ws[tx * 4 + 3][k];
            acc[0][0] += a0 * w0; acc[0][1] += a0 * w1; acc[0][2] += a0 * w2; acc[0][3] += a0 * w3;
            acc[1][0] += a1 * w0; acc[1][1] += a1 * w1; acc[1][2] += a1 * w2; acc[1][3] += a1 * w3;
            acc[2][0] += a2 * w0; acc[2][1] += a2 * w1; acc[2][2] += a2 * w2; acc[2][3] += a2 * w3;
            acc[3][0] += a3 * w0; acc[3][1] += a3 * w1; acc[3][2] += a3 * w2; acc[3][3] += a3 * w3;
        }
        __syncthreads();
    }

#pragma unroll
    for (int i = 0; i < 4; ++i) {
        int m = arow + ty * 4 + i;
#pragma unroll
        for (int j = 0; j < 4; ++j) {
            int n = bcol + tx * 4 + j;
            float v = acc[i][j] + bias[n];
            if (split_heads) {
                int b = m / TT, t = m % TT, h = n / HD, dh = n % HD;
                C[(((size_t)b * NH + h) * TT + t) * HD + dh] = v;
            } else {
                C[(size_t)m * N + n] = v;
            }
        }
    }
}

// ---------- MFMA attention with exact register-resident top-64 ----------
__global__ void __launch_bounds__(1024) attn_topk(
    const float* __restrict__ Q, const float* __restrict__ K,
    const float* __restrict__ V, const void* __restrict__ maskp,
    const int* __restrict__ flags, float* __restrict__ O)
{
    __shared__ float s_S[QT][KT + 1];        // 16 x 257 f32 = 16.4 KB
    __shared__ int   s_selk[QT][SELCAP];
    __shared__ float s_selw[QT][SELCAP];

    const int tid = threadIdx.x, lane = tid & 63, wv = tid >> 6;
    const int qt = blockIdx.x, bh = blockIdx.y;
    const int b = bh >> 4, h = bh & 15;
    const int mode = flags[0], causal = flags[1];
    const size_t hb = (size_t)bh * (size_t)TT * HD;
    const int r0 = qt * QT;
    const int gq = r0 + wv;              // this wave's q row (global)

    // ---- Q fragments (scaled by dh^-0.5, split hi/lo bf16) ----
    short8x qhi[2], qlo[2];
#pragma unroll
    for (int kh = 0; kh < 2; ++kh) {
        const float* qp = Q + hb + (size_t)(r0 + (lane & 15)) * HD + (lane >> 4) * 8 + kh * 32;
        float4 a = *(const float4*)qp, c = *(const float4*)(qp + 4);
        float f[8] = {a.x, a.y, a.z, a.w, c.x, c.y, c.z, c.w};
#pragma unroll
        for (int i = 0; i < 8; ++i) {
            float x = f[i] * 0.125f;
            short hi16 = bf16_rne(x);
            qhi[kh][i] = hi16;
            qlo[kh][i] = bf16_rne(x - bf16_to_f(hi16));
        }
    }

    // ---- mask bits: lane's 32 keys, key = (i>>2)*KT + (i&3)*64 + lane ----
    uint32_t mbits = 0;
#pragma unroll
    for (int i = 0; i < 32; ++i) {
        int key = (i >> 2) * KT + (i & 3) * 64 + lane;
        if (mask_at(maskp, mode, b * TT + key)) mbits |= (1u << i);
    }

    uint32_t lgo[32];
#pragma unroll
    for (int i = 0; i < 32; ++i) lgo[i] = ORD_NEG;

    const int lastT = causal ? ((r0 + QT - 1) >> 8) : 7;

#pragma unroll
    for (int t = 0; t < 8; ++t) {
        if (t <= lastT) {                 // block-uniform
            __syncthreads();              // prev tile's S reads done
            const float* kp = K + hb + (size_t)(t * KT + wv * 16 + (lane & 15)) * HD + (lane >> 4) * 8;
            float4 k0 = *(const float4*)kp,        k1 = *(const float4*)(kp + 4);
            float4 k2 = *(const float4*)(kp + 32), k3 = *(const float4*)(kp + 36);
            float f0[8] = {k0.x, k0.y, k0.z, k0.w, k1.x, k1.y, k1.z, k1.w};
            float f1[8] = {k2.x, k2.y, k2.z, k2.w, k3.x, k3.y, k3.z, k3.w};
            short8x bhi0, blo0, bhi1, blo1;
#pragma unroll
            for (int i = 0; i < 8; ++i) {
                short h0 = bf16_rne(f0[i]); bhi0[i] = h0; blo0[i] = bf16_rne(f0[i] - bf16_to_f(h0));
                short h1 = bf16_rne(f1[i]); bhi1[i] = h1; blo1[i] = bf16_rne(f1[i] - bf16_to_f(h1));
            }
            floatx4 acc = {0.f, 0.f, 0.f, 0.f};
            acc = __builtin_amdgcn_mfma_f32_16x16x32_bf16(qhi[0], bhi0, acc, 0, 0, 0);
            acc = __builtin_amdgcn_mfma_f32_16x16x32_bf16(qhi[0], blo0, acc, 0, 0, 0);
            acc = __builtin_amdgcn_mfma_f32_16x16x32_bf16(qlo[0], bhi0, acc, 0, 0, 0);
            acc = __builtin_amdgcn_mfma_f32_16x16x32_bf16(qhi[1], bhi1, acc, 0, 0, 0);
            acc = __builtin_amdgcn_mfma_f32_16x16x32_bf16(qhi[1], blo1, acc, 0, 0, 0);
            acc = __builtin_amdgcn_mfma_f32_16x16x32_bf16(qlo[1], bhi1, acc, 0, 0, 0);
#pragma unroll
            for (int j = 0; j < 4; ++j)
                s_S[(lane >> 4) * 4 + j][wv * 16 + (lane & 15)] = acc[j];
            __syncthreads();
#pragma unroll
            for (int j = 0; j < 4; ++j) {
                float sv = s_S[wv][j * 64 + lane];
                int key = t * KT + j * 64 + lane;
                bool blocked = ((mbits >> (t * 4 + j)) & 1u) || (causal && key > gq);
                lgo[t * 4 + j] = blocked ? ORD_NEG : ord_u32(sv);
            }
        }
    }

    // ---- epilogue: exact top-64 select + softmax + sparse A*V ----
    uint32_t mo = 0; int nv = 0;
#pragma unroll
    for (int i = 0; i < 32; ++i) {
        uint32_t u = lgo[i];
        mo = u > mo ? u : mo;
        nv += (u > ORD_NEG) ? 1 : 0;
    }
#pragma unroll
    for (int off = 1; off < 64; off <<= 1) {
        uint32_t mu = (uint32_t)__shfl_xor((int)mo, off, 64);
        mo = mu > mo ? mu : mo;
        nv += __shfl_xor(nv, off, 64);
    }

    float outv;
    if (nv == 0) {
        float a0 = 0.f, a1 = 0.f, a2 = 0.f, a3 = 0.f;
        for (int j = 0; j < TT; j += 4) {
            a0 += V[hb + (size_t)(j + 0) * HD + lane];
            a1 += V[hb + (size_t)(j + 1) * HD + lane];
            a2 += V[hb + (size_t)(j + 2) * HD + lane];
            a3 += V[hb + (size_t)(j + 3) * HD + lane];
        }
        outv = (a0 + a1 + a2 + a3) * (1.0f / TT);
    } else {
        const float m = unord(mo);
        uint32_t lo = ord_u32(m - 15.0f);
        int c0 = 0;
#pragma unroll
        for (int i = 0; i < 32; ++i) c0 += (lgo[i] >= lo) ? 1 : 0;
#pragma unroll
        for (int off = 1; off < 64; off <<= 1) c0 += __shfl_xor(c0, off, 64);

        uint32_t thr = lo;
        if (c0 > TOPK) {
            uint32_t hi = mo;
            while (hi - lo > 1u) {
                uint32_t mid = lo + ((hi - lo) >> 1);
                int c = 0;
#pragma unroll
                for (int i = 0; i < 32; ++i) c += (lgo[i] >= mid) ? 1 : 0;
#pragma unroll
                for (int off = 1; off < 64; off <<= 1) c += __shfl_xor(c, off, 64);
                if (c == TOPK) { lo = mid; break; }
                if (c > TOPK) lo = mid; else hi = mid;
            }
            thr = lo;
        }

        int nsel = 0; float Sp = 0.f;
#pragma unroll
        for (int i = 0; i < 32; ++i) {
            uint32_t u = lgo[i];
            float w = 0.f;
            if (u >= thr) w = __expf(unord(u) - m);
            Sp += w;
            nsel += (w > 0.f) ? 1 : 0;
            lgo[i] = (w > 0.f) ? __float_as_uint(w) : 0u;
        }
        float S = Sp;
#pragma unroll
        for (int off = 1; off < 64; off <<= 1) S += __shfl_xor(S, off, 64);
        int incl = nsel;
#pragma unroll
        for (int off = 1; off < 64; off <<= 1) {
            int t2 = __shfl_up(incl, off, 64);
            if (lane >= off) incl += t2;
        }
        int base = incl - nsel;
        int cnt  = __shfl(incl, 63, 64);
        int pos = base;
#pragma unroll
        for (int i = 0; i < 32; ++i) {
            float w = __uint_as_float(lgo[i]);
            if (w > 0.f) {
                if (pos < SELCAP) {
                    s_selk[wv][pos] = (i >> 2) * KT + (i & 3) * 64 + lane;
                    s_selw[wv][pos] = w;
                }
                ++pos;
            }
        }
        if (cnt > SELCAP) cnt = SELCAP;
        float acc = 0.f;
        int i2 = 0;
        for (; i2 + 4 <= cnt; i2 += 4) {
            int   ka = s_selk[wv][i2],     kb = s_selk[wv][i2 + 1];
            int   kc = s_selk[wv][i2 + 2], kd = s_selk[wv][i2 + 3];
            float wa = s_selw[wv][i2],     wb = s_selw[wv][i2 + 1];
            float wc = s_selw[wv][i2 + 2], wd = s_selw[wv][i2 + 3];
            acc += wa * V[hb + (size_t)ka * HD + lane];
            acc += wb * V[hb + (size_t)kb * HD + lane];
            acc += wc * V[hb + (size_t)kc * HD + lane];
            acc += wd * V[hb + (size_t)kd * HD + lane];
        }
        for (; i2 < cnt; ++i2)
            acc += s_selw[wv][i2] * V[hb + (size_t)s_selk[wv][i2] * HD + lane];
        outv = acc / S;
    }
    O[((size_t)b * TT + gq) * DD + h * HD + lane] = outv;
}

// ---------- launch ----------
extern "C" void kernel_launch(void* const* d_in, const int* in_sizes, int n_in,
                              void* d_out, int out_size, void* d_ws, size_t ws_size,
                              hipStream_t stream) {
    const float* x  = (const float*)d_in[0];
    const float* Wq = (const float*)d_in[1];
    const float* bq = (const float*)d_in[2];
    const float* Wk = (const float*)d_in[3];
    const float* bk = (const float*)d_in[4];
    const float* Wv = (const float*)d_in[5];
    const float* bv = (const float*)d_in[6];
    const float* Wo = (const float*)d_in[7];
    const float* bo = (const float*)d_in[8];
    const void*  maskp = d_in[9];
    const int*   causalp = (const int*)d_in[10];
    float* out = (float*)d_out;

    char* ws = (char*)d_ws;
    const size_t TEN = (size_t)BB * TT * DD * sizeof(float);  // 16.78 MB
    const size_t WSZ = (size_t)DD * DD * 2;                   // 2 MB (bf16 weight)
    const size_t NEED = 6 * TEN + 4096;

    float* Q = (float*)(ws);
    float* K = (float*)(ws + TEN);
    float* V = (float*)(ws + 2 * TEN);
    float* O = (float*)(ws + 3 * TEN);

    if (ws_size >= NEED) {
        short* xh = (short*)(ws + 4 * TEN);
        short* xl = xh + (size_t)BB * TT * DD;
        char*  wb = ws + 5 * TEN;
        short* wqh = (short*)(wb);            short* wql = (short*)(wb + WSZ);
        short* wkh = (short*)(wb + 2 * WSZ);  short* wkl = (short*)(wb + 3 * WSZ);
        short* wvh = (short*)(wb + 4 * WSZ);  short* wvl = (short*)(wb + 5 * WSZ);
        short* woh = (short*)(wb + 6 * WSZ);  short* wol = (short*)(wb + 7 * WSZ);
        int* flags = (int*)(ws + 6 * TEN);

        detect_kernel<<<1, 256, 0, stream>>>((const unsigned char*)maskp, causalp, flags);

        const int nx4 = BB * TT * DD / 4, nw4 = DD * DD / 4;
        split_f32<<<(nx4 + 255) / 256, 256, 0, stream>>>(x, xh, xl, nx4);
        split_f32<<<(nw4 + 255) / 256, 256, 0, stream>>>(Wq, wqh, wql, nw4);
        split_f32<<<(nw4 + 255) / 256, 256, 0, stream>>>(Wk, wkh, wkl, nw4);
        split_f32<<<(nw4 + 255) / 256, 256, 0, stream>>>(Wv, wvh, wvl, nw4);
        split_f32<<<(nw4 + 255) / 256, 256, 0, stream>>>(Wo, woh, wol, nw4);

        dim3 gg(DD / 64, (BB * TT) / 128);
        gemm_bf16s<<<gg, 256, 0, stream>>>(xh, xl, wqh, wql, bq, Q, 1);
        gemm_bf16s<<<gg, 256, 0, stream>>>(xh, xl, wkh, wkl, bk, K, 1);
        gemm_bf16s<<<gg, 256, 0, stream>>>(xh, xl, wvh, wvl, bv, V, 1);

        dim3 ag(TT / QT, BB * NH);
        attn_topk<<<ag, 1024, 0, stream>>>(Q, K, V, maskp, flags, O);

        split_f32<<<(nx4 + 255) / 256, 256, 0, stream>>>(O, xh, xl, nx4);  // reuse as Oh/Ol
        gemm_bf16s<<<gg, 256, 0, stream>>>(xh, xl, woh, wol, bo, out, 0);
    } else {
        int* flags = (int*)(ws + 4 * TEN);
        detect_kernel<<<1, 256, 0, stream>>>((const unsigned char*)maskp, causalp, flags);
        dim3 gg(DD / 64, (BB * TT) / 64);
        gemm_xwt<<<gg, 256, 0, stream>>>(x, Wq, bq, Q, BB * TT, DD, DD, 1);
        gemm_xwt<<<gg, 256, 0, stream>>>(x, Wk, bk, K, BB * TT, DD, DD, 1);
        gemm_xwt<<<gg, 256, 0, stream>>>(x, Wv, bv, V, BB * TT, DD, DD, 1);
        dim3 ag(TT / QT, BB * NH);
        attn_topk<<<ag, 1024, 0, stream>>>(Q, K, V, maskp, flags, O);
        gemm_xwt<<<gg, 256, 0, stream>>>(O, Wo, bo, out, BB * TT, DD, DD, 0);
    }
}

// Round 5
// 864.796 us; speedup vs baseline: 3.8754x; 1.2234x over previous
//
#include <hip/hip_runtime.h>
#include <hip/hip_bf16.h>
#include <stdint.h>

#define BB 2
#define TT 2048
#define DD 1024
#define NH 16
#define HD 64
#define TOPK 64
#define NEGF (-3.402823466e38f)
#define ORD_NEG 0x00800000u  // ord_u32(NEGF)
#define QT 16                // q-rows per block (1 per wave)
#define KT 256               // keys per tile
#define SELCAP 96

typedef short short8x __attribute__((ext_vector_type(8)));
typedef float floatx4 __attribute__((ext_vector_type(4)));

// ---------- helpers ----------
__device__ __forceinline__ uint32_t ord_u32(float x) {
    uint32_t b = __float_as_uint(x);
    return (b & 0x80000000u) ? ~b : (b | 0x80000000u);
}
__device__ __forceinline__ float unord(uint32_t u) {
    uint32_t b = (u & 0x80000000u) ? (u ^ 0x80000000u) : ~u;
    return __uint_as_float(b);
}
__device__ __forceinline__ short bf16_rne(float x) {
    uint32_t u = __float_as_uint(x);
    u += 0x7FFFu + ((u >> 16) & 1u);
    return (short)(u >> 16);
}
__device__ __forceinline__ float bf16_to_f(short h) {
    return __uint_as_float(((uint32_t)(uint16_t)h) << 16);
}
__device__ __forceinline__ bool mask_at(const void* m, int mode, int idx) {
    if (mode == 0) return ((const int*)m)[idx] != 0;
    if (mode == 1) return ((const unsigned char*)m)[idx] != 0;
    return ((const float*)m)[idx] != 0.0f;
}

// ---------- mask detection + transposed bitmask build ----------
// Mt[b*64 + l] bit s = mask[b][l + 64*s]  (s = t*4+j for attn's key layout)
__global__ void build_flags(const unsigned char* raw, const int* causalp,
                            int* flags, uint32_t* Mt) {
    __shared__ int odd_nz, big, s_mode;
    if (threadIdx.x == 0) { odd_nz = 0; big = 0; }
    __syncthreads();
    for (int i = threadIdx.x; i < BB * TT; i += 256) {
        unsigned char c = raw[i];
        if ((i & 3) && c) atomicOr(&odd_nz, 1);
        if (c > 1) atomicOr(&big, 1);
    }
    __syncthreads();
    if (threadIdx.x == 0) {
        int mode = odd_nz ? (big ? 2 : 1) : 0;
        s_mode = mode;
        flags[0] = mode;
        flags[1] = (causalp[0] != 0) ? 1 : 0;
    }
    __syncthreads();
    const int mode = s_mode;
    if (threadIdx.x < BB * 64) {
        int bb = threadIdx.x >> 6, l = threadIdx.x & 63;
        uint32_t w = 0;
        for (int s = 0; s < 32; ++s)
            if (mask_at(raw, mode, bb * TT + l + 64 * s)) w |= (1u << s);
        Mt[threadIdx.x] = w;
    }
}

// ---------- f32 -> (hi, lo) bf16 split (with scale) ----------
__global__ void __launch_bounds__(256) split_f32(
    const float* __restrict__ in, short* __restrict__ hi, short* __restrict__ lo,
    int n4, float scale)
{
    int i = blockIdx.x * blockDim.x + threadIdx.x;
    if (i >= n4) return;
    float4 v = ((const float4*)in)[i];
    float f[4] = {v.x * scale, v.y * scale, v.z * scale, v.w * scale};
    short hh[4], ll[4];
#pragma unroll
    for (int j = 0; j < 4; ++j) {
        hh[j] = bf16_rne(f[j]);
        ll[j] = bf16_rne(f[j] - bf16_to_f(hh[j]));
    }
    short4 h4; h4.x = hh[0]; h4.y = hh[1]; h4.z = hh[2]; h4.w = hh[3];
    short4 l4; l4.x = ll[0]; l4.y = ll[1]; l4.z = ll[2]; l4.w = ll[3];
    ((short4*)hi)[i] = h4;
    ((short4*)lo)[i] = l4;
}

// ---------- split-bf16 MFMA GEMM: C[m,n] = sum_k A[m,k]*W[n,k] + bias[n] ----------
// Fixed shape M=BB*TT=4096, N=DD, K=DD. LDS-free: fragments straight from L2.
// mode 0: f32 row-major; mode 1: f32 split-heads; mode 2: bf16 hi/lo split-heads (scaled)
__global__ void __launch_bounds__(256) gemm_bf16s(
    const short* __restrict__ Ah, const short* __restrict__ Al,
    const short* __restrict__ Bh, const short* __restrict__ Bl,
    const float* __restrict__ bias, float* __restrict__ Cf,
    short* __restrict__ Ch, short* __restrict__ Cl, float scale, int mode)
{
    const int tid = threadIdx.x, lane = tid & 63, wv = tid >> 6;
    const int wr = wv >> 1, wc = wv & 1;
    const int m0 = blockIdx.y * 128 + wr * 64;
    const int n0 = blockIdx.x * 64 + wc * 32;
    const int lrow = lane & 15, lk = (lane >> 4) * 8;

    floatx4 acc[4][2];
#pragma unroll
    for (int i = 0; i < 4; ++i)
#pragma unroll
        for (int j = 0; j < 2; ++j) acc[i][j] = (floatx4){0.f, 0.f, 0.f, 0.f};

    for (int kk = 0; kk < DD; kk += 32) {
        short8x ah[4], al[4], bh[2], bl[2];
#pragma unroll
        for (int mb = 0; mb < 4; ++mb) {
            size_t off = (size_t)(m0 + mb * 16 + lrow) * DD + kk + lk;
            ah[mb] = *(const short8x*)(Ah + off);
            al[mb] = *(const short8x*)(Al + off);
        }
#pragma unroll
        for (int nb = 0; nb < 2; ++nb) {
            size_t off = (size_t)(n0 + nb * 16 + lrow) * DD + kk + lk;
            bh[nb] = *(const short8x*)(Bh + off);
            bl[nb] = *(const short8x*)(Bl + off);
        }
#pragma unroll
        for (int mb = 0; mb < 4; ++mb)
#pragma unroll
            for (int nb = 0; nb < 2; ++nb) {
                acc[mb][nb] = __builtin_amdgcn_mfma_f32_16x16x32_bf16(ah[mb], bh[nb], acc[mb][nb], 0, 0, 0);
                acc[mb][nb] = __builtin_amdgcn_mfma_f32_16x16x32_bf16(ah[mb], bl[nb], acc[mb][nb], 0, 0, 0);
                acc[mb][nb] = __builtin_amdgcn_mfma_f32_16x16x32_bf16(al[mb], bh[nb], acc[mb][nb], 0, 0, 0);
            }
    }

#pragma unroll
    for (int mb = 0; mb < 4; ++mb)
#pragma unroll
        for (int nb = 0; nb < 2; ++nb) {
            int n = n0 + nb * 16 + lrow;
            float bv = bias[n];
#pragma unroll
            for (int j = 0; j < 4; ++j) {
                int m = m0 + mb * 16 + (lane >> 4) * 4 + j;
                float v = acc[mb][nb][j] + bv;
                if (mode == 0) {
                    Cf[(size_t)m * DD + n] = v;
                } else {
                    int b = m >> 11, t = m & (TT - 1), h = n >> 6, dh = n & (HD - 1);
                    size_t idx = (((size_t)b * NH + h) * TT + t) * HD + dh;
                    if (mode == 1) {
                        Cf[idx] = v;
                    } else {
                        v *= scale;
                        short hi16 = bf16_rne(v);
                        Ch[idx] = hi16;
                        Cl[idx] = bf16_rne(v - bf16_to_f(hi16));
                    }
                }
            }
        }
}

// ---------- f32 GEMM (fallback if workspace too small) ----------
__global__ void __launch_bounds__(256) gemm_xwt(
    const float* __restrict__ A, const float* __restrict__ W,
    const float* __restrict__ bias, float* __restrict__ C,
    int M, int N, int K, int split_heads)
{
    __shared__ float As[64][17];
    __shared__ float Ws[64][17];
    const int tid = threadIdx.x;
    const int tx = tid & 15, ty = tid >> 4;
    const int arow = blockIdx.y * 64, bcol = blockIdx.x * 64;
    float acc[4][4] = {};

    for (int k0 = 0; k0 < K; k0 += 16) {
        const int r = tid >> 2, c = (tid & 3) * 4;
        float4 a4 = *(const float4*)(A + (size_t)(arow + r) * K + k0 + c);
        As[r][c] = a4.x; As[r][c + 1] = a4.y; As[r][c + 2] = a4.z; As[r][c + 3] = a4.w;
        float4 w4 = *(const float4*)(W + (size_t)(bcol + r) * K + k0 + c);
        Ws[r][c] = w4.x; Ws[r][c + 1] = w4.y; Ws[r][c + 2] = w4.z; Ws[r][c + 3] = w4.w;
        __syncthreads();
#pragma unroll
        for (int k = 0; k < 16; ++k) {
            float a0 = As[ty * 4 + 0][k], a1 = As[ty * 4 + 1][k];
            float a2 = As[ty * 4 + 2][k], a3 = As[ty * 4 + 3][k];
            float w0 = Ws[tx * 4 + 0][k], w1 = Ws[tx * 4 + 1][k];
            float w2 = Ws[tx * 4 + 2][k], w3 = Ws[tx * 4 + 3][k];
            acc[0][0] += a0 * w0; acc[0][1] += a0 * w1; acc[0][2] += a0 * w2; acc[0][3] += a0 * w3;
            acc[1][0] += a1 * w0; acc[1][1] += a1 * w1; acc[1][2] += a1 * w2; acc[1][3] += a1 * w3;
            acc[2][0] += a2 * w0; acc[2][1] += a2 * w1; acc[2][2] += a2 * w2; acc[2][3] += a2 * w3;
            acc[3][0] += a3 * w0; acc[3][1] += a3 * w1; acc[3][2] += a3 * w2; acc[3][3] += a3 * w3;
        }
        __syncthreads();
    }

#pragma unroll
    for (int i = 0; i < 4; ++i) {
        int m = arow + ty * 4 + i;
#pragma unroll
        for (int j = 0; j < 4; ++j) {
            int n = bcol + tx * 4 + j;
            float v = acc[i][j] + bias[n];
            if (split_heads) {
                int b = m / TT, t = m % TT, h = n / HD, dh = n % HD;
                C[(((size_t)b * NH + h) * TT + t) * HD + dh] = v;
            } else {
                C[(size_t)m * N + n] = v;
            }
        }
    }
}

// ---------- MFMA attention with exact register-resident top-64 ----------
__global__ void __launch_bounds__(1024) attn_topk(
    const short* __restrict__ Qhi, const short* __restrict__ Qlo,
    const short* __restrict__ Khi, const short* __restrict__ Klo,
    const float* __restrict__ V, const uint32_t* __restrict__ Mt,
    const int* __restrict__ flags, float* __restrict__ O)
{
    __shared__ float s_S[2][QT][KT + 1];     // 32.9 KB (double-buffered)
    __shared__ int   s_selk[QT][SELCAP];
    __shared__ float s_selw[QT][SELCAP];

    const int tid = threadIdx.x, lane = tid & 63, wv = tid >> 6;
    const int qt = blockIdx.x, bh = blockIdx.y;
    const int b = bh >> 4, h = bh & 15;
    const int causal = flags[1];
    const size_t hb = (size_t)bh * (size_t)TT * HD;
    const int r0 = qt * QT;
    const int gq = r0 + wv;              // this wave's q row (global)

    // ---- Q fragments (pre-scaled, pre-split by GEMM epilogue) ----
    short8x qhi[2], qlo[2];
    {
        const size_t qoff = hb + (size_t)(r0 + (lane & 15)) * HD + (lane >> 4) * 8;
        qhi[0] = *(const short8x*)(Qhi + qoff);
        qhi[1] = *(const short8x*)(Qhi + qoff + 32);
        qlo[0] = *(const short8x*)(Qlo + qoff);
        qlo[1] = *(const short8x*)(Qlo + qoff + 32);
    }

    // one u32 of transposed mask bits: bit (t*4+j) = mask for key t*256+j*64+lane
    const uint32_t mwords = Mt[b * 64 + lane];

    uint32_t lgo[32];
#pragma unroll
    for (int i = 0; i < 32; ++i) lgo[i] = ORD_NEG;

    const int lastT = causal ? ((r0 + QT - 1) >> 8) : 7;

#pragma unroll
    for (int t = 0; t < 8; ++t) {
        if (t <= lastT) {                 // block-uniform
            const size_t koff = hb + (size_t)(t * KT + wv * 16 + (lane & 15)) * HD + (lane >> 4) * 8;
            short8x kh0 = *(const short8x*)(Khi + koff);
            short8x kh1 = *(const short8x*)(Khi + koff + 32);
            short8x kl0 = *(const short8x*)(Klo + koff);
            short8x kl1 = *(const short8x*)(Klo + koff + 32);
            floatx4 acc = {0.f, 0.f, 0.f, 0.f};
            acc = __builtin_amdgcn_mfma_f32_16x16x32_bf16(qhi[0], kh0, acc, 0, 0, 0);
            acc = __builtin_amdgcn_mfma_f32_16x16x32_bf16(qhi[0], kl0, acc, 0, 0, 0);
            acc = __builtin_amdgcn_mfma_f32_16x16x32_bf16(qlo[0], kh0, acc, 0, 0, 0);
            acc = __builtin_amdgcn_mfma_f32_16x16x32_bf16(qhi[1], kh1, acc, 0, 0, 0);
            acc = __builtin_amdgcn_mfma_f32_16x16x32_bf16(qhi[1], kl1, acc, 0, 0, 0);
            acc = __builtin_amdgcn_mfma_f32_16x16x32_bf16(qlo[1], kh1, acc, 0, 0, 0);
#pragma unroll
            for (int j = 0; j < 4; ++j)
                s_S[t & 1][(lane >> 4) * 4 + j][wv * 16 + (lane & 15)] = acc[j];
            __syncthreads();              // single barrier per tile (dbuf)
#pragma unroll
            for (int j = 0; j < 4; ++j) {
                float sv = s_S[t & 1][wv][j * 64 + lane];
                int key = t * KT + j * 64 + lane;
                bool blocked = ((mwords >> (t * 4 + j)) & 1u) || (causal && key > gq);
                lgo[t * 4 + j] = blocked ? ORD_NEG : ord_u32(sv);
            }
        }
    }

    // ---- epilogue: exact top-64 select + softmax + sparse A*V ----
    uint32_t mo = 0; int nv = 0;
#pragma unroll
    for (int i = 0; i < 32; ++i) {
        uint32_t u = lgo[i];
        mo = u > mo ? u : mo;
        nv += (u > ORD_NEG) ? 1 : 0;
    }
#pragma unroll
    for (int off = 1; off < 64; off <<= 1) {
        uint32_t mu = (uint32_t)__shfl_xor((int)mo, off, 64);
        mo = mu > mo ? mu : mo;
        nv += __shfl_xor(nv, off, 64);
    }

    auto wcount = [&](uint32_t thrv) -> int {
        int c = 0;
#pragma unroll
        for (int i = 0; i < 32; ++i) c += (lgo[i] >= thrv) ? 1 : 0;
#pragma unroll
        for (int off = 1; off < 64; off <<= 1) c += __shfl_xor(c, off, 64);
        return c;
    };

    float outv;
    if (nv == 0) {
        // fully blocked row: reference softmax is uniform over ALL keys
        float a0 = 0.f, a1 = 0.f, a2 = 0.f, a3 = 0.f;
        for (int j = 0; j < TT; j += 4) {
            a0 += V[hb + (size_t)(j + 0) * HD + lane];
            a1 += V[hb + (size_t)(j + 1) * HD + lane];
            a2 += V[hb + (size_t)(j + 2) * HD + lane];
            a3 += V[hb + (size_t)(j + 3) * HD + lane];
        }
        outv = (a0 + a1 + a2 + a3) * (1.0f / TT);
    } else {
        const float mF = unord(mo);
        // adaptive probe cascade, then early-exit bisection
        uint32_t thr = 0; uint32_t lo_b = 0, hi_b = 0; int done = 0;
        {
            uint32_t p1 = ord_u32(mF - 2.0f);
            int c1 = wcount(p1);
            if (c1 == TOPK) { thr = p1; done = 1; }
            else if (c1 > TOPK) { lo_b = p1; hi_b = mo; }
            else {
                uint32_t p2 = ord_u32(mF - 4.0f);
                int c2 = wcount(p2);
                if (c2 == TOPK) { thr = p2; done = 1; }
                else if (c2 > TOPK) { lo_b = p2; hi_b = p1; }
                else {
                    uint32_t p3 = ord_u32(mF - 15.0f);
                    int c3 = wcount(p3);
                    if (c3 <= TOPK) { thr = p3; done = 1; }  // <64 valid-ish keys: take all (rest < e^-15)
                    else { lo_b = p3; hi_b = p2; }
                }
            }
        }
        if (!done) {
            while (hi_b - lo_b > 1u) {
                uint32_t mid = lo_b + ((hi_b - lo_b) >> 1);
                int c = wcount(mid);
                if (c == TOPK) { lo_b = mid; break; }
                if (c > TOPK) lo_b = mid; else hi_b = mid;
            }
            thr = lo_b;
        }

        // weights: overwrite lgo with w bits
        int nsel = 0; float Sp = 0.f;
#pragma unroll
        for (int i = 0; i < 32; ++i) {
            uint32_t u = lgo[i];
            float w = 0.f;
            if (u >= thr) w = __expf(unord(u) - mF);
            Sp += w;
            nsel += (w > 0.f) ? 1 : 0;
            lgo[i] = (w > 0.f) ? __float_as_uint(w) : 0u;
        }
        float S = Sp;
#pragma unroll
        for (int off = 1; off < 64; off <<= 1) S += __shfl_xor(S, off, 64);
        int incl = nsel;
#pragma unroll
        for (int off = 1; off < 64; off <<= 1) {
            int t2 = __shfl_up(incl, off, 64);
            if (lane >= off) incl += t2;
        }
        int base = incl - nsel;
        int cnt  = __shfl(incl, 63, 64);
        int pos = base;
#pragma unroll
        for (int i = 0; i < 32; ++i) {
            float w = __uint_as_float(lgo[i]);
            if (w > 0.f) {
                if (pos < SELCAP) {
                    s_selk[wv][pos] = (i >> 2) * KT + (i & 3) * 64 + lane;
                    s_selw[wv][pos] = w;
                }
                ++pos;
            }
        }
        if (cnt > SELCAP) cnt = SELCAP;
        float acc = 0.f;
        int i2 = 0;
        for (; i2 + 4 <= cnt; i2 += 4) {
            int   ka = s_selk[wv][i2],     kb = s_selk[wv][i2 + 1];
            int   kc = s_selk[wv][i2 + 2], kd = s_selk[wv][i2 + 3];
            float wa = s_selw[wv][i2],     wb = s_selw[wv][i2 + 1];
            float wc = s_selw[wv][i2 + 2], wd = s_selw[wv][i2 + 3];
            acc += wa * V[hb + (size_t)ka * HD + lane];
            acc += wb * V[hb + (size_t)kb * HD + lane];
            acc += wc * V[hb + (size_t)kc * HD + lane];
            acc += wd * V[hb + (size_t)kd * HD + lane];
        }
        for (; i2 < cnt; ++i2)
            acc += s_selw[wv][i2] * V[hb + (size_t)s_selk[wv][i2] * HD + lane];
        outv = acc / S;
    }
    O[((size_t)b * TT + gq) * DD + h * HD + lane] = outv;
}

// ---------- launch ----------
extern "C" void kernel_launch(void* const* d_in, const int* in_sizes, int n_in,
                              void* d_out, int out_size, void* d_ws, size_t ws_size,
                              hipStream_t stream) {
    const float* x  = (const float*)d_in[0];
    const float* Wq = (const float*)d_in[1];
    const float* bq = (const float*)d_in[2];
    const float* Wk = (const float*)d_in[3];
    const float* bk = (const float*)d_in[4];
    const float* Wv = (const float*)d_in[5];
    const float* bv = (const float*)d_in[6];
    const float* Wo = (const float*)d_in[7];
    const float* bo = (const float*)d_in[8];
    const void*  maskp = d_in[9];
    const int*   causalp = (const int*)d_in[10];
    float* out = (float*)d_out;

    char* ws = (char*)d_ws;
    const size_t TEN  = (size_t)BB * TT * DD * sizeof(float);  // 16.78 MB
    const size_t HTEN = TEN / 2;                               // bf16 tensor
    const size_t WSZ  = (size_t)DD * DD * 2;                   // 2 MB bf16 weight
    const size_t NEED = 6 * TEN + 4096;

    const int nx4 = BB * TT * DD / 4, nw4 = DD * DD / 4;
    dim3 gg(DD / 64, (BB * TT) / 128);
    dim3 ag(TT / QT, BB * NH);

    if (ws_size >= NEED) {
        float* O    = (float*)(ws);
        float* Vf   = (float*)(ws + TEN);
        short* xh   = (short*)(ws + 2 * TEN);
        short* xl   = (short*)(ws + 2 * TEN + HTEN);
        short* Qhi  = (short*)(ws + 3 * TEN);
        short* Qlo  = (short*)(ws + 3 * TEN + HTEN);
        short* Khi  = (short*)(ws + 4 * TEN);
        short* Klo  = (short*)(ws + 4 * TEN + HTEN);
        char*  wb   = ws + 5 * TEN;
        short* wqh = (short*)(wb);            short* wql = (short*)(wb + WSZ);
        short* wkh = (short*)(wb + 2 * WSZ);  short* wkl = (short*)(wb + 3 * WSZ);
        short* wvh = (short*)(wb + 4 * WSZ);  short* wvl = (short*)(wb + 5 * WSZ);
        short* woh = (short*)(wb + 6 * WSZ);  short* wol = (short*)(wb + 7 * WSZ);
        int*      flags = (int*)(wb + 8 * WSZ);
        uint32_t* Mt    = (uint32_t*)(wb + 8 * WSZ + 256);

        build_flags<<<1, 256, 0, stream>>>((const unsigned char*)maskp, causalp, flags, Mt);

        split_f32<<<(nx4 + 255) / 256, 256, 0, stream>>>(x, xh, xl, nx4, 1.0f);
        split_f32<<<(nw4 + 255) / 256, 256, 0, stream>>>(Wq, wqh, wql, nw4, 1.0f);
        split_f32<<<(nw4 + 255) / 256, 256, 0, stream>>>(Wk, wkh, wkl, nw4, 1.0f);
        split_f32<<<(nw4 + 255) / 256, 256, 0, stream>>>(Wv, wvh, wvl, nw4, 1.0f);
        split_f32<<<(nw4 + 255) / 256, 256, 0, stream>>>(Wo, woh, wol, nw4, 1.0f);

        gemm_bf16s<<<gg, 256, 0, stream>>>(xh, xl, wqh, wql, bq, nullptr, Qhi, Qlo, 0.125f, 2);
        gemm_bf16s<<<gg, 256, 0, stream>>>(xh, xl, wkh, wkl, bk, nullptr, Khi, Klo, 1.0f, 2);
        gemm_bf16s<<<gg, 256, 0, stream>>>(xh, xl, wvh, wvl, bv, Vf, nullptr, nullptr, 1.0f, 1);

        attn_topk<<<ag, 1024, 0, stream>>>(Qhi, Qlo, Khi, Klo, Vf, Mt, flags, O);

        split_f32<<<(nx4 + 255) / 256, 256, 0, stream>>>(O, xh, xl, nx4, 1.0f);  // reuse xh/xl
        gemm_bf16s<<<gg, 256, 0, stream>>>(xh, xl, woh, wol, bo, out, nullptr, nullptr, 1.0f, 0);
    } else {
        // fallback: f32 GEMMs, then split Q/K for the MFMA attention
        float* Qf  = (float*)(ws);
        float* Kf  = (float*)(ws + TEN);
        float* Vf  = (float*)(ws + 2 * TEN);
        float* O   = (float*)(ws + 3 * TEN);
        short* Qhi = (short*)(ws + 4 * TEN);
        short* Qlo = (short*)(ws + 4 * TEN + HTEN);
        short* Khi = (short*)(ws + 5 * TEN);
        short* Klo = (short*)(ws + 5 * TEN + HTEN);
        int*      flags = (int*)(ws + 6 * TEN);
        uint32_t* Mt    = (uint32_t*)(ws + 6 * TEN + 256);

        build_flags<<<1, 256, 0, stream>>>((const unsigned char*)maskp, causalp, flags, Mt);
        dim3 g2(DD / 64, (BB * TT) / 64);
        gemm_xwt<<<g2, 256, 0, stream>>>(x, Wq, bq, Qf, BB * TT, DD, DD, 1);
        gemm_xwt<<<g2, 256, 0, stream>>>(x, Wk, bk, Kf, BB * TT, DD, DD, 1);
        gemm_xwt<<<g2, 256, 0, stream>>>(x, Wv, bv, Vf, BB * TT, DD, DD, 1);
        split_f32<<<(nx4 + 255) / 256, 256, 0, stream>>>(Qf, Qhi, Qlo, nx4, 0.125f);
        split_f32<<<(nx4 + 255) / 256, 256, 0, stream>>>(Kf, Khi, Klo, nx4, 1.0f);
        attn_topk<<<ag, 1024, 0, stream>>>(Qhi, Qlo, Khi, Klo, Vf, Mt, flags, O);
        gemm_xwt<<<g2, 256, 0, stream>>>(O, Wo, bo, out, BB * TT, DD, DD, 0);
    }
}

// Round 6
// 817.354 us; speedup vs baseline: 4.1004x; 1.0580x over previous
//
#include <hip/hip_runtime.h>
#include <hip/hip_bf16.h>
#include <stdint.h>

#define BB 2
#define TT 2048
#define DD 1024
#define NH 16
#define HD 64
#define TOPK 64
#define NEGF (-3.402823466e38f)
#define ORD_NEG 0x00800000u  // ord_u32(NEGF)
#define QT 16                // q-rows per block (1 per wave)
#define KT 256               // keys per tile
#define SELCAP 96

typedef short short8x __attribute__((ext_vector_type(8)));
typedef float floatx4 __attribute__((ext_vector_type(4)));

// ---------- helpers ----------
__device__ __forceinline__ uint32_t ord_u32(float x) {
    uint32_t b = __float_as_uint(x);
    return (b & 0x80000000u) ? ~b : (b | 0x80000000u);
}
__device__ __forceinline__ float unord(uint32_t u) {
    uint32_t b = (u & 0x80000000u) ? (u ^ 0x80000000u) : ~u;
    return __uint_as_float(b);
}
__device__ __forceinline__ short bf16_rne(float x) {
    uint32_t u = __float_as_uint(x);
    u += 0x7FFFu + ((u >> 16) & 1u);
    return (short)(u >> 16);
}
__device__ __forceinline__ float bf16_to_f(short h) {
    return __uint_as_float(((uint32_t)(uint16_t)h) << 16);
}
__device__ __forceinline__ bool mask_at(const void* m, int mode, int idx) {
    if (mode == 0) return ((const int*)m)[idx] != 0;
    if (mode == 1) return ((const unsigned char*)m)[idx] != 0;
    return ((const float*)m)[idx] != 0.0f;
}

// ---------- DPP wave-64 reductions (VALU-only, ~25cy vs ~200cy shfl chain) ----------
// row_shr 1/2/4/8 -> lane 15/31/47/63 hold row sums; bcast15(+rows1,3), bcast31(+rows2,3)
// -> lane 63 = full reduction; readlane(63) = wave-uniform result.
__device__ __forceinline__ int dpp_wsum(int v) {
    v += __builtin_amdgcn_update_dpp(0, v, 0x111, 0xf, 0xf, true);
    v += __builtin_amdgcn_update_dpp(0, v, 0x112, 0xf, 0xf, true);
    v += __builtin_amdgcn_update_dpp(0, v, 0x114, 0xf, 0xf, true);
    v += __builtin_amdgcn_update_dpp(0, v, 0x118, 0xf, 0xf, true);
    v += __builtin_amdgcn_update_dpp(0, v, 0x142, 0xa, 0xf, true);
    v += __builtin_amdgcn_update_dpp(0, v, 0x143, 0xc, 0xf, true);
    return __builtin_amdgcn_readlane(v, 63);
}
__device__ __forceinline__ uint32_t dpp_wumax(uint32_t v) {
    uint32_t t;
    t = (uint32_t)__builtin_amdgcn_update_dpp(0, (int)v, 0x111, 0xf, 0xf, true); v = v > t ? v : t;
    t = (uint32_t)__builtin_amdgcn_update_dpp(0, (int)v, 0x112, 0xf, 0xf, true); v = v > t ? v : t;
    t = (uint32_t)__builtin_amdgcn_update_dpp(0, (int)v, 0x114, 0xf, 0xf, true); v = v > t ? v : t;
    t = (uint32_t)__builtin_amdgcn_update_dpp(0, (int)v, 0x118, 0xf, 0xf, true); v = v > t ? v : t;
    t = (uint32_t)__builtin_amdgcn_update_dpp(0, (int)v, 0x142, 0xa, 0xf, true); v = v > t ? v : t;
    t = (uint32_t)__builtin_amdgcn_update_dpp(0, (int)v, 0x143, 0xc, 0xf, true); v = v > t ? v : t;
    return (uint32_t)__builtin_amdgcn_readlane((int)v, 63);
}
__device__ __forceinline__ float dpp_fsum(float v) {
    v += __uint_as_float((uint32_t)__builtin_amdgcn_update_dpp(0, (int)__float_as_uint(v), 0x111, 0xf, 0xf, true));
    v += __uint_as_float((uint32_t)__builtin_amdgcn_update_dpp(0, (int)__float_as_uint(v), 0x112, 0xf, 0xf, true));
    v += __uint_as_float((uint32_t)__builtin_amdgcn_update_dpp(0, (int)__float_as_uint(v), 0x114, 0xf, 0xf, true));
    v += __uint_as_float((uint32_t)__builtin_amdgcn_update_dpp(0, (int)__float_as_uint(v), 0x118, 0xf, 0xf, true));
    v += __uint_as_float((uint32_t)__builtin_amdgcn_update_dpp(0, (int)__float_as_uint(v), 0x142, 0xa, 0xf, true));
    v += __uint_as_float((uint32_t)__builtin_amdgcn_update_dpp(0, (int)__float_as_uint(v), 0x143, 0xc, 0xf, true));
    return __uint_as_float((uint32_t)__builtin_amdgcn_readlane((int)__float_as_uint(v), 63));
}

// ---------- mask detection + transposed bitmask build ----------
// Mt[b*64 + l] bit s = mask[b][l + 64*s]
__global__ void __launch_bounds__(1024) build_flags(
    const unsigned char* raw, const int* causalp, int* flags, uint32_t* Mt)
{
    __shared__ int odd_nz, big, s_mode;
    __shared__ uint32_t smt[BB * 64];
    const int tid = threadIdx.x;
    if (tid == 0) { odd_nz = 0; big = 0; }
    if (tid < BB * 64) smt[tid] = 0;
    __syncthreads();
    for (int i = tid; i < BB * TT; i += 1024) {
        unsigned char c = raw[i];
        if ((i & 3) && c) atomicOr(&odd_nz, 1);
        if (c > 1) atomicOr(&big, 1);
    }
    __syncthreads();
    if (tid == 0) {
        int mode = odd_nz ? (big ? 2 : 1) : 0;
        s_mode = mode;
        flags[0] = mode;
        flags[1] = (causalp[0] != 0) ? 1 : 0;
    }
    __syncthreads();
    const int mode = s_mode;
    const int w = tid >> 3, g = tid & 7;   // word 0..127, chunk 0..7
    const int bb = w >> 6, l = w & 63;
    uint32_t bits = 0;
#pragma unroll
    for (int si = 0; si < 4; ++si) {
        int s = g * 4 + si;
        if (mask_at(raw, mode, bb * TT + l + 64 * s)) bits |= (1u << s);
    }
    if (bits) atomicOr(&smt[w], bits);
    __syncthreads();
    if (tid < BB * 64) Mt[tid] = smt[tid];
}

// ---------- f32 -> (hi, lo) bf16 split (with scale) ----------
__global__ void __launch_bounds__(256) split_f32(
    const float* __restrict__ in, short* __restrict__ hi, short* __restrict__ lo,
    int n4, float scale)
{
    int i = blockIdx.x * blockDim.x + threadIdx.x;
    if (i >= n4) return;
    float4 v = ((const float4*)in)[i];
    float f[4] = {v.x * scale, v.y * scale, v.z * scale, v.w * scale};
    short hh[4], ll[4];
#pragma unroll
    for (int j = 0; j < 4; ++j) {
        hh[j] = bf16_rne(f[j]);
        ll[j] = bf16_rne(f[j] - bf16_to_f(hh[j]));
    }
    short4 h4; h4.x = hh[0]; h4.y = hh[1]; h4.z = hh[2]; h4.w = hh[3];
    short4 l4; l4.x = ll[0]; l4.y = ll[1]; l4.z = ll[2]; l4.w = ll[3];
    ((short4*)hi)[i] = h4;
    ((short4*)lo)[i] = l4;
}

// ---------- 4 weights split in one launch (blockIdx.y selects weight) ----------
__global__ void __launch_bounds__(256) split_w4(
    const float* __restrict__ W0, const float* __restrict__ W1,
    const float* __restrict__ W2, const float* __restrict__ W3,
    short* __restrict__ h0, short* __restrict__ l0, short* __restrict__ h1, short* __restrict__ l1,
    short* __restrict__ h2, short* __restrict__ l2, short* __restrict__ h3, short* __restrict__ l3,
    int n4)
{
    int i = blockIdx.x * blockDim.x + threadIdx.x;
    if (i >= n4) return;
    const int w = blockIdx.y;
    const float* in = (w == 0) ? W0 : (w == 1) ? W1 : (w == 2) ? W2 : W3;
    short* hi = (w == 0) ? h0 : (w == 1) ? h1 : (w == 2) ? h2 : h3;
    short* lo = (w == 0) ? l0 : (w == 1) ? l1 : (w == 2) ? l2 : l3;
    float4 v = ((const float4*)in)[i];
    float f[4] = {v.x, v.y, v.z, v.w};
    short hh[4], ll[4];
#pragma unroll
    for (int j = 0; j < 4; ++j) {
        hh[j] = bf16_rne(f[j]);
        ll[j] = bf16_rne(f[j] - bf16_to_f(hh[j]));
    }
    short4 h4; h4.x = hh[0]; h4.y = hh[1]; h4.z = hh[2]; h4.w = hh[3];
    short4 l4; l4.x = ll[0]; l4.y = ll[1]; l4.z = ll[2]; l4.w = ll[3];
    ((short4*)hi)[i] = h4;
    ((short4*)lo)[i] = l4;
}

// ---------- split-bf16 MFMA GEMM with double-buffered fragment prefetch ----------
// C[m,n] = sum_k A[m,k]*W[n,k] + bias[n]; M=4096, N=K=DD.
// mode 0: f32 row-major; mode 1: f32 split-heads; mode 2: bf16 hi/lo split-heads (scaled)
__global__ void __launch_bounds__(256) gemm_bf16s(
    const short* __restrict__ Ah, const short* __restrict__ Al,
    const short* __restrict__ Bh, const short* __restrict__ Bl,
    const float* __restrict__ bias, float* __restrict__ Cf,
    short* __restrict__ Ch, short* __restrict__ Cl, float scale, int mode)
{
    const int tid = threadIdx.x, lane = tid & 63, wv = tid >> 6;
    const int wr = wv >> 1, wc = wv & 1;
    const int m0 = blockIdx.y * 128 + wr * 64;
    const int n0 = blockIdx.x * 64 + wc * 32;
    const int lrow = lane & 15, lk = (lane >> 4) * 8;

    floatx4 acc[4][2];
#pragma unroll
    for (int i = 0; i < 4; ++i)
#pragma unroll
        for (int j = 0; j < 2; ++j) acc[i][j] = (floatx4){0.f, 0.f, 0.f, 0.f};

    auto ldfr = [&](int kk, short8x* pah, short8x* pal, short8x* pbh, short8x* pbl) {
#pragma unroll
        for (int mb = 0; mb < 4; ++mb) {
            size_t off = (size_t)(m0 + mb * 16 + lrow) * DD + kk + lk;
            pah[mb] = *(const short8x*)(Ah + off);
            pal[mb] = *(const short8x*)(Al + off);
        }
#pragma unroll
        for (int nb = 0; nb < 2; ++nb) {
            size_t off = (size_t)(n0 + nb * 16 + lrow) * DD + kk + lk;
            pbh[nb] = *(const short8x*)(Bh + off);
            pbl[nb] = *(const short8x*)(Bl + off);
        }
    };
    auto domfma = [&](short8x* pah, short8x* pal, short8x* pbh, short8x* pbl) {
#pragma unroll
        for (int mb = 0; mb < 4; ++mb)
#pragma unroll
            for (int nb = 0; nb < 2; ++nb) {
                acc[mb][nb] = __builtin_amdgcn_mfma_f32_16x16x32_bf16(pah[mb], pbh[nb], acc[mb][nb], 0, 0, 0);
                acc[mb][nb] = __builtin_amdgcn_mfma_f32_16x16x32_bf16(pah[mb], pbl[nb], acc[mb][nb], 0, 0, 0);
                acc[mb][nb] = __builtin_amdgcn_mfma_f32_16x16x32_bf16(pal[mb], pbh[nb], acc[mb][nb], 0, 0, 0);
            }
    };

    short8x A0[4], L0[4], B0[2], C0[2];   // buffer 0 (named, static indexing)
    short8x A1[4], L1[4], B1[2], C1[2];   // buffer 1
    ldfr(0, A0, L0, B0, C0);
    for (int kk = 0; kk < DD; kk += 64) {
        ldfr(kk + 32, A1, L1, B1, C1);
        domfma(A0, L0, B0, C0);
        if (kk + 64 < DD) ldfr(kk + 64, A0, L0, B0, C0);
        domfma(A1, L1, B1, C1);
    }

#pragma unroll
    for (int mb = 0; mb < 4; ++mb)
#pragma unroll
        for (int nb = 0; nb < 2; ++nb) {
            int n = n0 + nb * 16 + lrow;
            float bv = bias[n];
#pragma unroll
            for (int j = 0; j < 4; ++j) {
                int m = m0 + mb * 16 + (lane >> 4) * 4 + j;
                float v = acc[mb][nb][j] + bv;
                if (mode == 0) {
                    Cf[(size_t)m * DD + n] = v;
                } else {
                    int b = m >> 11, t = m & (TT - 1), h = n >> 6, dh = n & (HD - 1);
                    size_t idx = (((size_t)b * NH + h) * TT + t) * HD + dh;
                    if (mode == 1) {
                        Cf[idx] = v;
                    } else {
                        v *= scale;
                        short hi16 = bf16_rne(v);
                        Ch[idx] = hi16;
                        Cl[idx] = bf16_rne(v - bf16_to_f(hi16));
                    }
                }
            }
        }
}

// ---------- f32 GEMM (fallback if workspace too small) ----------
__global__ void __launch_bounds__(256) gemm_xwt(
    const float* __restrict__ A, const float* __restrict__ W,
    const float* __restrict__ bias, float* __restrict__ C,
    int M, int N, int K, int split_heads)
{
    __shared__ float As[64][17];
    __shared__ float Ws[64][17];
    const int tid = threadIdx.x;
    const int tx = tid & 15, ty = tid >> 4;
    const int arow = blockIdx.y * 64, bcol = blockIdx.x * 64;
    float acc[4][4] = {};

    for (int k0 = 0; k0 < K; k0 += 16) {
        const int r = tid >> 2, c = (tid & 3) * 4;
        float4 a4 = *(const float4*)(A + (size_t)(arow + r) * K + k0 + c);
        As[r][c] = a4.x; As[r][c + 1] = a4.y; As[r][c + 2] = a4.z; As[r][c + 3] = a4.w;
        float4 w4 = *(const float4*)(W + (size_t)(bcol + r) * K + k0 + c);
        Ws[r][c] = w4.x; Ws[r][c + 1] = w4.y; Ws[r][c + 2] = w4.z; Ws[r][c + 3] = w4.w;
        __syncthreads();
#pragma unroll
        for (int k = 0; k < 16; ++k) {
            float a0 = As[ty * 4 + 0][k], a1 = As[ty * 4 + 1][k];
            float a2 = As[ty * 4 + 2][k], a3 = As[ty * 4 + 3][k];
            float w0 = Ws[tx * 4 + 0][k], w1 = Ws[tx * 4 + 1][k];
            float w2 = Ws[tx * 4 + 2][k], w3 = Ws[tx * 4 + 3][k];
            acc[0][0] += a0 * w0; acc[0][1] += a0 * w1; acc[0][2] += a0 * w2; acc[0][3] += a0 * w3;
            acc[1][0] += a1 * w0; acc[1][1] += a1 * w1; acc[1][2] += a1 * w2; acc[1][3] += a1 * w3;
            acc[2][0] += a2 * w0; acc[2][1] += a2 * w1; acc[2][2] += a2 * w2; acc[2][3] += a2 * w3;
            acc[3][0] += a3 * w0; acc[3][1] += a3 * w1; acc[3][2] += a3 * w2; acc[3][3] += a3 * w3;
        }
        __syncthreads();
    }

#pragma unroll
    for (int i = 0; i < 4; ++i) {
        int m = arow + ty * 4 + i;
#pragma unroll
        for (int j = 0; j < 4; ++j) {
            int n = bcol + tx * 4 + j;
            float v = acc[i][j] + bias[n];
            if (split_heads) {
                int b = m / TT, t = m % TT, h = n / HD, dh = n % HD;
                C[(((size_t)b * NH + h) * TT + t) * HD + dh] = v;
            } else {
                C[(size_t)m * N + n] = v;
            }
        }
    }
}

// ---------- MFMA attention with exact register-resident top-64 ----------
__global__ void __launch_bounds__(1024) attn_topk(
    const short* __restrict__ Qhi, const short* __restrict__ Qlo,
    const short* __restrict__ Khi, const short* __restrict__ Klo,
    const float* __restrict__ V, const uint32_t* __restrict__ Mt,
    const int* __restrict__ flags, float* __restrict__ O)
{
    __shared__ float s_S[2][QT][KT + 1];     // 32.9 KB (double-buffered)
    __shared__ int2  s_sel[QT][SELCAP];      // packed (key<<6, w bits)

    const int tid = threadIdx.x, lane = tid & 63, wv = tid >> 6;
    const int qt = blockIdx.x, bh = blockIdx.y;
    const int b = bh >> 4, h = bh & 15;
    const int causal = flags[1];
    const size_t hb = (size_t)bh * (size_t)TT * HD;
    const int r0 = qt * QT;
    const int gq = r0 + wv;              // this wave's q row (global)
    const float* __restrict__ Vh = V + hb;

    // ---- Q fragments (pre-scaled, pre-split by GEMM epilogue) ----
    short8x qhi[2], qlo[2];
    {
        const size_t qoff = hb + (size_t)(r0 + (lane & 15)) * HD + (lane >> 4) * 8;
        qhi[0] = *(const short8x*)(Qhi + qoff);
        qhi[1] = *(const short8x*)(Qhi + qoff + 32);
        qlo[0] = *(const short8x*)(Qlo + qoff);
        qlo[1] = *(const short8x*)(Qlo + qoff + 32);
    }

    // one u32 of transposed mask bits: bit (t*4+j) = mask for key t*256+j*64+lane
    const uint32_t mwords = Mt[b * 64 + lane];

    uint32_t lgo[32];
#pragma unroll
    for (int i = 0; i < 32; ++i) lgo[i] = ORD_NEG;

    const int lastT = causal ? ((r0 + QT - 1) >> 8) : 7;

#pragma unroll
    for (int t = 0; t < 8; ++t) {
        if (t <= lastT) {                 // block-uniform
            const size_t koff = hb + (size_t)(t * KT + wv * 16 + (lane & 15)) * HD + (lane >> 4) * 8;
            short8x kh0 = *(const short8x*)(Khi + koff);
            short8x kh1 = *(const short8x*)(Khi + koff + 32);
            short8x kl0 = *(const short8x*)(Klo + koff);
            short8x kl1 = *(const short8x*)(Klo + koff + 32);
            floatx4 acc = {0.f, 0.f, 0.f, 0.f};
            acc = __builtin_amdgcn_mfma_f32_16x16x32_bf16(qhi[0], kh0, acc, 0, 0, 0);
            acc = __builtin_amdgcn_mfma_f32_16x16x32_bf16(qhi[0], kl0, acc, 0, 0, 0);
            acc = __builtin_amdgcn_mfma_f32_16x16x32_bf16(qlo[0], kh0, acc, 0, 0, 0);
            acc = __builtin_amdgcn_mfma_f32_16x16x32_bf16(qhi[1], kh1, acc, 0, 0, 0);
            acc = __builtin_amdgcn_mfma_f32_16x16x32_bf16(qhi[1], kl1, acc, 0, 0, 0);
            acc = __builtin_amdgcn_mfma_f32_16x16x32_bf16(qlo[1], kh1, acc, 0, 0, 0);
#pragma unroll
            for (int j = 0; j < 4; ++j)
                s_S[t & 1][(lane >> 4) * 4 + j][wv * 16 + (lane & 15)] = acc[j];
            __syncthreads();              // single barrier per tile (dbuf)
#pragma unroll
            for (int j = 0; j < 4; ++j) {
                float sv = s_S[t & 1][wv][j * 64 + lane];
                int key = t * KT + j * 64 + lane;
                bool blocked = ((mwords >> (t * 4 + j)) & 1u) || (causal && key > gq);
                lgo[t * 4 + j] = blocked ? ORD_NEG : ord_u32(sv);
            }
        }
    }

    // ---- epilogue: exact top-64 select + softmax + sparse A*V ----
    uint32_t moL = 0; int nvL = 0;
#pragma unroll
    for (int i = 0; i < 32; ++i) {
        uint32_t u = lgo[i];
        moL = u > moL ? u : moL;
        nvL += (u > ORD_NEG) ? 1 : 0;
    }
    const uint32_t mo = dpp_wumax(moL);
    const int nv = dpp_wsum(nvL);

    auto wcount = [&](uint32_t thrv) -> int {
        int c = 0;
#pragma unroll
        for (int i = 0; i < 32; ++i) c += (lgo[i] >= thrv) ? 1 : 0;
        return dpp_wsum(c);
    };

    float outv;
    if (nv == 0) {
        // fully blocked row: reference softmax is uniform over ALL keys
        float a0 = 0.f, a1 = 0.f, a2 = 0.f, a3 = 0.f;
        for (int j = 0; j < TT; j += 4) {
            a0 += Vh[(j + 0) * HD + lane];
            a1 += Vh[(j + 1) * HD + lane];
            a2 += Vh[(j + 2) * HD + lane];
            a3 += Vh[(j + 3) * HD + lane];
        }
        outv = (a0 + a1 + a2 + a3) * (1.0f / TT);
    } else {
        const float mF = unord(mo);
        // adaptive probe cascade, then early-exit bisection
        uint32_t thr = 0; uint32_t lo_b = 0, hi_b = 0; int done = 0;
        {
            uint32_t p1 = ord_u32(mF - 2.0f);
            int c1 = wcount(p1);
            if (c1 == TOPK) { thr = p1; done = 1; }
            else if (c1 > TOPK) { lo_b = p1; hi_b = mo; }
            else {
                uint32_t p2 = ord_u32(mF - 4.0f);
                int c2 = wcount(p2);
                if (c2 == TOPK) { thr = p2; done = 1; }
                else if (c2 > TOPK) { lo_b = p2; hi_b = p1; }
                else {
                    uint32_t p3 = ord_u32(mF - 15.0f);
                    int c3 = wcount(p3);
                    if (c3 <= TOPK) { thr = p3; done = 1; }  // <64 candidates: take all (rest < e^-15)
                    else { lo_b = p3; hi_b = p2; }
                }
            }
        }
        if (!done) {
            while (hi_b - lo_b > 1u) {
                uint32_t mid = lo_b + ((hi_b - lo_b) >> 1);
                int c = wcount(mid);
                if (c == TOPK) { lo_b = mid; break; }
                if (c > TOPK) lo_b = mid; else hi_b = mid;
            }
            thr = lo_b;
        }

        // weights: overwrite lgo with w bits
        int nsel = 0; float Sp = 0.f;
#pragma unroll
        for (int i = 0; i < 32; ++i) {
            uint32_t u = lgo[i];
            float w = 0.f;
            if (u >= thr) w = __expf(unord(u) - mF);
            Sp += w;
            nsel += (w > 0.f) ? 1 : 0;
            lgo[i] = (w > 0.f) ? __float_as_uint(w) : 0u;
        }
        const float S = dpp_fsum(Sp);
        int incl = nsel;
#pragma unroll
        for (int off = 1; off < 64; off <<= 1) {
            int t2 = __shfl_up(incl, off, 64);
            if (lane >= off) incl += t2;
        }
        int base = incl - nsel;
        int cnt  = __builtin_amdgcn_readlane(incl, 63);
        int pos = base;
#pragma unroll
        for (int i = 0; i < 32; ++i) {
            uint32_t wbits = lgo[i];
            if (wbits) {
                if (pos < SELCAP) {
                    int keyoff = (((i >> 2) * KT + (i & 3) * 64 + lane) << 6);
                    s_sel[wv][pos] = make_int2(keyoff, (int)wbits);
                }
                ++pos;
            }
        }
        if (cnt > SELCAP) cnt = SELCAP;
        // sparse A*V: packed ds_read_b64 (broadcast), lane = output dim
        float acc = 0.f;
        int i2 = 0;
        for (; i2 + 4 <= cnt; i2 += 4) {
            int2 e0 = s_sel[wv][i2],     e1 = s_sel[wv][i2 + 1];
            int2 e2 = s_sel[wv][i2 + 2], e3 = s_sel[wv][i2 + 3];
            acc += __int_as_float(e0.y) * Vh[e0.x + lane];
            acc += __int_as_float(e1.y) * Vh[e1.x + lane];
            acc += __int_as_float(e2.y) * Vh[e2.x + lane];
            acc += __int_as_float(e3.y) * Vh[e3.x + lane];
        }
        for (; i2 < cnt; ++i2) {
            int2 e = s_sel[wv][i2];
            acc += __int_as_float(e.y) * Vh[e.x + lane];
        }
        outv = acc / S;
    }
    O[((size_t)b * TT + gq) * DD + h * HD + lane] = outv;
}

// ---------- launch ----------
extern "C" void kernel_launch(void* const* d_in, const int* in_sizes, int n_in,
                              void* d_out, int out_size, void* d_ws, size_t ws_size,
                              hipStream_t stream) {
    const float* x  = (const float*)d_in[0];
    const float* Wq = (const float*)d_in[1];
    const float* bq = (const float*)d_in[2];
    const float* Wk = (const float*)d_in[3];
    const float* bk = (const float*)d_in[4];
    const float* Wv = (const float*)d_in[5];
    const float* bv = (const float*)d_in[6];
    const float* Wo = (const float*)d_in[7];
    const float* bo = (const float*)d_in[8];
    const void*  maskp = d_in[9];
    const int*   causalp = (const int*)d_in[10];
    float* out = (float*)d_out;

    char* ws = (char*)d_ws;
    const size_t TEN  = (size_t)BB * TT * DD * sizeof(float);  // 16.78 MB
    const size_t HTEN = TEN / 2;                               // bf16 tensor
    const size_t WSZ  = (size_t)DD * DD * 2;                   // 2 MB bf16 weight
    const size_t NEED = 6 * TEN + 4096;

    const int nx4 = BB * TT * DD / 4, nw4 = DD * DD / 4;
    dim3 gg(DD / 64, (BB * TT) / 128);
    dim3 ag(TT / QT, BB * NH);

    if (ws_size >= NEED) {
        float* O    = (float*)(ws);
        float* Vf   = (float*)(ws + TEN);
        short* xh   = (short*)(ws + 2 * TEN);
        short* xl   = (short*)(ws + 2 * TEN + HTEN);
        short* Qhi  = (short*)(ws + 3 * TEN);
        short* Qlo  = (short*)(ws + 3 * TEN + HTEN);
        short* Khi  = (short*)(ws + 4 * TEN);
        short* Klo  = (short*)(ws + 4 * TEN + HTEN);
        char*  wb   = ws + 5 * TEN;
        short* wqh = (short*)(wb);            short* wql = (short*)(wb + WSZ);
        short* wkh = (short*)(wb + 2 * WSZ);  short* wkl = (short*)(wb + 3 * WSZ);
        short* wvh = (short*)(wb + 4 * WSZ);  short* wvl = (short*)(wb + 5 * WSZ);
        short* woh = (short*)(wb + 6 * WSZ);  short* wol = (short*)(wb + 7 * WSZ);
        int*      flags = (int*)(wb + 8 * WSZ);
        uint32_t* Mt    = (uint32_t*)(wb + 8 * WSZ + 256);

        build_flags<<<1, 1024, 0, stream>>>((const unsigned char*)maskp, causalp, flags, Mt);

        split_f32<<<(nx4 + 255) / 256, 256, 0, stream>>>(x, xh, xl, nx4, 1.0f);
        dim3 wg((nw4 + 255) / 256, 4);
        split_w4<<<wg, 256, 0, stream>>>(Wq, Wk, Wv, Wo,
                                         wqh, wql, wkh, wkl, wvh, wvl, woh, wol, nw4);

        gemm_bf16s<<<gg, 256, 0, stream>>>(xh, xl, wqh, wql, bq, nullptr, Qhi, Qlo, 0.125f, 2);
        gemm_bf16s<<<gg, 256, 0, stream>>>(xh, xl, wkh, wkl, bk, nullptr, Khi, Klo, 1.0f, 2);
        gemm_bf16s<<<gg, 256, 0, stream>>>(xh, xl, wvh, wvl, bv, Vf, nullptr, nullptr, 1.0f, 1);

        attn_topk<<<ag, 1024, 0, stream>>>(Qhi, Qlo, Khi, Klo, Vf, Mt, flags, O);

        split_f32<<<(nx4 + 255) / 256, 256, 0, stream>>>(O, xh, xl, nx4, 1.0f);  // reuse xh/xl
        gemm_bf16s<<<gg, 256, 0, stream>>>(xh, xl, woh, wol, bo, out, nullptr, nullptr, 1.0f, 0);
    } else {
        // fallback: f32 GEMMs, then split Q/K for the MFMA attention
        float* Qf  = (float*)(ws);
        float* Kf  = (float*)(ws + TEN);
        float* Vf  = (float*)(ws + 2 * TEN);
        float* O   = (float*)(ws + 3 * TEN);
        short* Qhi = (short*)(ws + 4 * TEN);
        short* Qlo = (short*)(ws + 4 * TEN + HTEN);
        short* Khi = (short*)(ws + 5 * TEN);
        short* Klo = (short*)(ws + 5 * TEN + HTEN);
        int*      flags = (int*)(ws + 6 * TEN);
        uint32_t* Mt    = (uint32_t*)(ws + 6 * TEN + 256);

        build_flags<<<1, 1024, 0, stream>>>((const unsigned char*)maskp, causalp, flags, Mt);
        dim3 g2(DD / 64, (BB * TT) / 64);
        gemm_xwt<<<g2, 256, 0, stream>>>(x, Wq, bq, Qf, BB * TT, DD, DD, 1);
        gemm_xwt<<<g2, 256, 0, stream>>>(x, Wk, bk, Kf, BB * TT, DD, DD, 1);
        gemm_xwt<<<g2, 256, 0, stream>>>(x, Wv, bv, Vf, BB * TT, DD, DD, 1);
        split_f32<<<(nx4 + 255) / 256, 256, 0, stream>>>(Qf, Qhi, Qlo, nx4, 0.125f);
        split_f32<<<(nx4 + 255) / 256, 256, 0, stream>>>(Kf, Khi, Klo, nx4, 1.0f);
        attn_topk<<<ag, 1024, 0, stream>>>(Qhi, Qlo, Khi, Klo, Vf, Mt, flags, O);
        gemm_xwt<<<g2, 256, 0, stream>>>(O, Wo, bo, out, BB * TT, DD, DD, 0);
    }
}